// Round 3
// baseline (16960.039 us; speedup 1.0000x reference)
//
#include <hip/hip_runtime.h>
#include <hip/hip_bf16.h>

typedef unsigned short u16;

#define ND 30000
#define NP 30000
#define NS 10000
#define E_DD 1000000
#define E_DP 1000000
#define E_PD 1000000
#define E_PP 1000000
#define E_SD 500000

__device__ __forceinline__ float bf2f(u16 u) {
  union { unsigned int i; float f; } c; c.i = ((unsigned int)u) << 16; return c.f;
}
__device__ __forceinline__ u16 f2bf(float f) {
  union { float f; unsigned int i; } c; c.f = f;
  unsigned int u = c.i;
  unsigned int r = (u + 0x7fffu + ((u >> 16) & 1u)) >> 16;
  return (u16)r;
}

// ---------------------------------------------------------------------------
// Input dtype detection: for fp32 data, even u16s are mantissa halves
// (random bits -> ~16% sane exponent); for bf16 data ~100% sane.
// ---------------------------------------------------------------------------
__global__ void k_detect(const void* x, int* flag) {
  if (threadIdx.x == 0 && blockIdx.x == 0) {
    const u16* p = (const u16*)x;
    int sane = 0;
    for (int i = 0; i < 256; ++i) {
      const u16 v = p[2 * i];
      const int e = (v >> 7) & 0xff;
      sane += (e >= 100 && e <= 140) ? 1 : 0;
    }
    *flag = (sane >= 200) ? 1 : 0;   // 1 = inputs are bf16, 0 = fp32
  }
}

__device__ __forceinline__ float ld_in(const void* p, int i, int isbf) {
  return isbf ? bf2f(((const u16*)p)[i]) : ((const float*)p)[i];
}

// ---------------------------------------------------------------------------
// z = x @ W (per-node GEMV vs LDS-staged W). Optional: z_out bf16,
// el = sum_d(z*al) per head, er = sum_d(z*ar) per head.
// ---------------------------------------------------------------------------
__global__ __launch_bounds__(256) void k_transform(
    const void* __restrict__ x, const void* __restrict__ W,
    const void* __restrict__ al, const void* __restrict__ ar,
    u16* __restrict__ z_out, float* __restrict__ el_out, float* __restrict__ er_out,
    int N, const int* __restrict__ flagp)
{
  __shared__ u16 Ws[16384];
  __shared__ float xs[2][128];
  __shared__ float alS[128], arS[128];
  const int tid = threadIdx.x;
  const int sub = tid >> 7;
  const int j = tid & 127;
  const int isbf = *flagp;

  if (isbf) {
    uint4* dst4 = (uint4*)Ws;
    const uint4* src4 = (const uint4*)W;
    for (int i = tid; i < 2048; i += 256) dst4[i] = src4[i];
  } else {
    const float* Wf = (const float*)W;
    for (int i = tid; i < 16384; i += 256) Ws[i] = f2bf(Wf[i]);
  }
  if (tid < 128) {
    alS[tid] = al ? ld_in(al, tid, isbf) : 0.f;
    arS[tid] = ar ? ld_in(ar, tid, isbf) : 0.f;
  }
  __syncthreads();

  const bool has_al = (al != nullptr);
  const bool has_ar = (ar != nullptr);
  const bool has_z  = (z_out != nullptr);

  for (int n0 = blockIdx.x * 2; n0 < N; n0 += gridDim.x * 2) {
    const int n = n0 + sub;
    const bool act = (n < N);
    if (act) xs[sub][j] = ld_in(x, n * 128 + j, isbf);
    __syncthreads();

    float acc = 0.f;
    #pragma unroll 8
    for (int k = 0; k < 128; ++k)
      acc = fmaf(xs[sub][k], bf2f(Ws[k * 128 + j]), acc);

    if (act && has_z) z_out[n * 128 + j] = f2bf(acc);

    if (has_al) {
      float p = acc * alS[j];
      p += __shfl_xor(p, 1); p += __shfl_xor(p, 2);
      p += __shfl_xor(p, 4); p += __shfl_xor(p, 8);
      if (act && (j & 15) == 0) el_out[n * 8 + (j >> 4)] = p;
    }
    if (has_ar) {
      float p = acc * arS[j];
      p += __shfl_xor(p, 1); p += __shfl_xor(p, 2);
      p += __shfl_xor(p, 4); p += __shfl_xor(p, 8);
      if (act && (j & 15) == 0) er_out[n * 8 + (j >> 4)] = p;
    }
    __syncthreads();
  }
}

// ---------------------------------------------------------------------------
// Edge pass: 16 lanes/edge. ex = exp(leakyrelu(el[src]+er[dst])).
// den[dst,h] += ex ; num[dst,:] += ex * z[src,:]  (fp32 HW atomics).
// Softmax shift-invariance: no segment-max pass needed.
// ---------------------------------------------------------------------------
__global__ __launch_bounds__(256) void k_edge(
    const int* __restrict__ src, const int* __restrict__ dst,
    const float* __restrict__ el, const float* __restrict__ er,
    const u16* __restrict__ z, float* __restrict__ den, float* __restrict__ num,
    int E)
{
  const int gid = blockIdx.x * 256 + threadIdx.x;
  const int e = gid >> 4;
  if (e >= E) return;
  const int j = gid & 15;
  const int s = src[e];
  const int d = dst[e];
  const int h = j >> 1;

  float eh = el[s * 8 + h] + er[d * 8 + h];
  eh = (eh >= 0.f) ? eh : 0.2f * eh;
  eh = fminf(eh, 60.f);               // inf-insurance; never binds on valid data
  const float ex = __expf(eh);

  if ((j & 1) == 0) unsafeAtomicAdd(&den[d * 8 + h], ex);

  const uint4 zv = *reinterpret_cast<const uint4*>(z + (s * 128 + j * 8));
  float* dp = num + (d * 128 + j * 8);
  const unsigned int wbits[4] = {zv.x, zv.y, zv.z, zv.w};
  #pragma unroll
  for (int t = 0; t < 4; ++t) {
    const float lo = bf2f((u16)(wbits[t] & 0xffffu));
    const float hi = bf2f((u16)(wbits[t] >> 16));
    unsafeAtomicAdd(dp + 2 * t,     ex * lo);
    unsafeAtomicAdd(dp + 2 * t + 1, ex * hi);
  }
}

// ---------------------------------------------------------------------------
// feats[n][r][:] = num/max(den,1e-9) + b   (bf16, strided into stacked buf)
// ---------------------------------------------------------------------------
__global__ __launch_bounds__(256) void k_finalize(
    const float* __restrict__ num, const float* __restrict__ den,
    const void* __restrict__ b, u16* __restrict__ feats, int rowStride, int N,
    const int* __restrict__ flagp)
{
  const int i = blockIdx.x * 256 + threadIdx.x;
  if (i >= N * 128) return;
  const int isbf = *flagp;
  const int n = i >> 7;
  const int j = i & 127;
  const float dn = den[n * 8 + (j >> 4)];
  const float v = num[i] / fmaxf(dn, 1e-9f) + ld_in(b, j, isbf);
  feats[n * rowStride + j] = f2bf(v);
}

// ---------------------------------------------------------------------------
// Semantic score: s[row] = tanh(f_row @ W1 + b1) @ W2 + b2, rows = N*R bf16
// ---------------------------------------------------------------------------
__global__ __launch_bounds__(256) void k_sem_score(
    const u16* __restrict__ f,
    const void* __restrict__ W1, const void* __restrict__ b1,
    const void* __restrict__ W2, const void* __restrict__ b2,
    float* __restrict__ s_out, int total, const int* __restrict__ flagp)
{
  __shared__ u16 W1s[16384];
  __shared__ float xs[2][128];
  __shared__ float b1S[128], W2S[128];
  __shared__ float wsum[2][2];
  const int tid = threadIdx.x;
  const int sub = tid >> 7;
  const int j = tid & 127;
  const int isbf = *flagp;

  if (isbf) {
    uint4* dst4 = (uint4*)W1s;
    const uint4* src4 = (const uint4*)W1;
    for (int i = tid; i < 2048; i += 256) dst4[i] = src4[i];
  } else {
    const float* Wf = (const float*)W1;
    for (int i = tid; i < 16384; i += 256) W1s[i] = f2bf(Wf[i]);
  }
  if (tid < 128) { b1S[tid] = ld_in(b1, tid, isbf); W2S[tid] = ld_in(W2, tid, isbf); }
  __syncthreads();
  const float b2v = ld_in(b2, 0, isbf);

  for (int r0 = blockIdx.x * 2; r0 < total; r0 += gridDim.x * 2) {
    const int row = r0 + sub;
    const bool act = (row < total);
    if (act) xs[sub][j] = bf2f(f[row * 128 + j]);
    __syncthreads();

    float acc = b1S[j];
    #pragma unroll 8
    for (int k = 0; k < 128; ++k)
      acc = fmaf(xs[sub][k], bf2f(W1s[k * 128 + j]), acc);

    float p = tanhf(acc) * W2S[j];
    p += __shfl_xor(p, 1);  p += __shfl_xor(p, 2);  p += __shfl_xor(p, 4);
    p += __shfl_xor(p, 8);  p += __shfl_xor(p, 16); p += __shfl_xor(p, 32);
    const int lane = tid & 63;
    const int wv = (tid >> 6) & 1;
    if (lane == 0) wsum[sub][wv] = p;
    __syncthreads();
    if (act && j == 0) s_out[row] = wsum[sub][0] + wsum[sub][1] + b2v;
    __syncthreads();
  }
}

// ---------------------------------------------------------------------------
// Combine: softmax over R relation scores, weighted sum of bf16 feats.
// Output dtype matches input dtype (flag).
// ---------------------------------------------------------------------------
__global__ __launch_bounds__(256) void k_combine(
    const u16* __restrict__ feats, const float* __restrict__ s,
    void* __restrict__ out, int outBase, int N, int R,
    const int* __restrict__ flagp)
{
  const int i = blockIdx.x * 256 + threadIdx.x;
  if (i >= N * 128) return;
  const int isbf = *flagp;
  const int n = i >> 7;
  const int j = i & 127;
  const float* sr = s + n * R;
  const float s0v = sr[0];
  const float s1v = sr[1];
  const float s2v = (R == 3) ? sr[2] : -3.4e38f;
  const float m = fmaxf(fmaxf(s0v, s1v), s2v);
  const float w0 = __expf(s0v - m);
  const float w1 = __expf(s1v - m);
  const float w2 = (R == 3) ? __expf(s2v - m) : 0.f;
  const float inv = 1.f / (w0 + w1 + w2);
  float acc = w0 * bf2f(feats[(n * R + 0) * 128 + j])
            + w1 * bf2f(feats[(n * R + 1) * 128 + j]);
  if (R == 3) acc += w2 * bf2f(feats[(n * R + 2) * 128 + j]);
  const float v = acc * inv;
  if (isbf) ((u16*)out)[outBase + i] = f2bf(v);
  else      ((float*)out)[outBase + i] = v;
}

extern "C" void kernel_launch(void* const* d_in, const int* in_sizes, int n_in,
                              void* d_out, int out_size, void* d_ws, size_t ws_size,
                              hipStream_t stream)
{
  (void)in_sizes; (void)n_in; (void)out_size; (void)ws_size;

  const void* h_drug = d_in[0];
  const void* h_prot = d_in[1];
  const void* h_se   = d_in[2];
  const void* W_dd = d_in[3];
  const void* al_dd = d_in[4];
  const void* ar_dd = d_in[5];
  const void* b_dd  = d_in[6];
  const void* W_dp = d_in[7];
  const void* al_dp = d_in[8];
  const void* ar_dp = d_in[9];
  const void* b_dp  = d_in[10];
  const void* W_pd = d_in[11];
  const void* al_pd = d_in[12];
  const void* ar_pd = d_in[13];
  const void* b_pd  = d_in[14];
  const void* W_pp = d_in[15];
  const void* al_pp = d_in[16];
  const void* ar_pp = d_in[17];
  const void* b_pp  = d_in[18];
  const void* W_sd = d_in[19];
  const void* al_sd = d_in[20];
  const void* ar_sd = d_in[21];
  const void* b_sd  = d_in[22];
  const void* W1 = d_in[23];
  const void* b1 = d_in[24];
  const void* W2 = d_in[25];
  const void* b2 = d_in[26];
  const int* src_dd = (const int*)d_in[27];
  const int* dst_dd = (const int*)d_in[28];
  const int* src_dp = (const int*)d_in[29];
  const int* dst_dp = (const int*)d_in[30];
  const int* src_pd = (const int*)d_in[31];
  const int* dst_pd = (const int*)d_in[32];
  const int* src_pp = (const int*)d_in[33];
  const int* dst_pp = (const int*)d_in[34];
  const int* src_sd = (const int*)d_in[35];
  const int* dst_sd = (const int*)d_in[36];

  // ---- workspace layout (49,320,004 bytes total) ----
  // num   fp32 [30000*128]       @ 0            (15.36 MB, per-relation, reused)
  // den   fp32 [30000*8]         @ 15,360,000   (0.96 MB, reused)
  // el    fp32 [30000*8]         @ 16,320,000   (reused)
  // er    fp32 [30000*8]         @ 17,280,000   (reused)
  // z     bf16 [30000*128]       @ 18,240,000   (7.68 MB, reused)
  // s     fp32 [90000]           @ 25,920,000
  // feats bf16 [30000*3*128]     @ 26,280,000   (23.04 MB; prot phase reuses)
  // flag  int                    @ 49,320,000
  char* w = (char*)d_ws;
  float* num = (float*)(w);
  float* den = (float*)(w + 15360000);
  float* el  = (float*)(w + 16320000);
  float* er  = (float*)(w + 17280000);
  u16*   z   = (u16*)  (w + 18240000);
  float* s   = (float*)(w + 25920000);
  u16*   feats = (u16*)(w + 26280000);
  int*   flag  = (int*) (w + 49320000);

  const dim3 blk(256);
  auto tg = [](int N) { int g = (N + 1) / 2; return dim3(g < 2048 ? g : 2048); };
  auto eg = [](long long E) { return dim3((unsigned)((E * 16 + 255) / 256)); };
  auto ng = [](int N) { return dim3((N * 128 + 255) / 256); };

  k_detect<<<dim3(1), dim3(64), 0, stream>>>(h_drug, flag);

  // ================= DRUG PHASE (relations dd, pd, sd; R=3) =================
  // --- dd (r=0) ---
  (void)hipMemsetAsync(w, 0, 16320000, stream);  // num+den
  k_transform<<<tg(ND), blk, 0, stream>>>(h_drug, W_dd, al_dd, ar_dd, z, el, er, ND, flag);
  k_edge<<<eg(E_DD), blk, 0, stream>>>(src_dd, dst_dd, el, er, z, den, num, E_DD);
  k_finalize<<<ng(ND), blk, 0, stream>>>(num, den, b_dd, feats + 0 * 128, 384, ND, flag);
  // --- pd (r=1) ---
  (void)hipMemsetAsync(w, 0, 16320000, stream);
  k_transform<<<tg(NP), blk, 0, stream>>>(h_prot, W_pd, al_pd, nullptr, z, el, nullptr, NP, flag);
  k_transform<<<tg(ND), blk, 0, stream>>>(h_drug, W_pd, nullptr, ar_pd, nullptr, nullptr, er, ND, flag);
  k_edge<<<eg(E_PD), blk, 0, stream>>>(src_pd, dst_pd, el, er, z, den, num, E_PD);
  k_finalize<<<ng(ND), blk, 0, stream>>>(num, den, b_pd, feats + 1 * 128, 384, ND, flag);
  // --- sd (r=2) ---
  (void)hipMemsetAsync(w, 0, 16320000, stream);
  k_transform<<<tg(NS), blk, 0, stream>>>(h_se, W_sd, al_sd, nullptr, z, el, nullptr, NS, flag);
  k_transform<<<tg(ND), blk, 0, stream>>>(h_drug, W_sd, nullptr, ar_sd, nullptr, nullptr, er, ND, flag);
  k_edge<<<eg(E_SD), blk, 0, stream>>>(src_sd, dst_sd, el, er, z, den, num, E_SD);
  k_finalize<<<ng(ND), blk, 0, stream>>>(num, den, b_sd, feats + 2 * 128, 384, ND, flag);
  // --- semantic + combine ---
  k_sem_score<<<dim3(2048), blk, 0, stream>>>(feats, W1, b1, W2, b2, s, ND * 3, flag);
  k_combine<<<ng(ND), blk, 0, stream>>>(feats, s, d_out, 0, ND, 3, flag);

  // ================ PROTEIN PHASE (relations dp, pp; R=2) ====================
  // --- dp (r=0) ---
  (void)hipMemsetAsync(w, 0, 16320000, stream);
  k_transform<<<tg(ND), blk, 0, stream>>>(h_drug, W_dp, al_dp, nullptr, z, el, nullptr, ND, flag);
  k_transform<<<tg(NP), blk, 0, stream>>>(h_prot, W_dp, nullptr, ar_dp, nullptr, nullptr, er, NP, flag);
  k_edge<<<eg(E_DP), blk, 0, stream>>>(src_dp, dst_dp, el, er, z, den, num, E_DP);
  k_finalize<<<ng(NP), blk, 0, stream>>>(num, den, b_dp, feats + 0 * 128, 256, NP, flag);
  // --- pp (r=1) ---
  (void)hipMemsetAsync(w, 0, 16320000, stream);
  k_transform<<<tg(NP), blk, 0, stream>>>(h_prot, W_pp, al_pp, ar_pp, z, el, er, NP, flag);
  k_edge<<<eg(E_PP), blk, 0, stream>>>(src_pp, dst_pp, el, er, z, den, num, E_PP);
  k_finalize<<<ng(NP), blk, 0, stream>>>(num, den, b_pp, feats + 1 * 128, 256, NP, flag);
  // --- semantic + combine ---
  k_sem_score<<<dim3(2048), blk, 0, stream>>>(feats, W1, b1, W2, b2, s, NP * 2, flag);
  k_combine<<<ng(NP), blk, 0, stream>>>(feats, s, d_out, ND * 128, NP, 2, flag);
}

// Round 4
// 2049.595 us; speedup vs baseline: 8.2748x; 8.2748x over previous
//
#include <hip/hip_runtime.h>
#include <hip/hip_bf16.h>

typedef unsigned short u16;

#define ND 30000
#define NP 30000
#define NS 10000
#define E_DD 1000000
#define E_DP 1000000
#define E_PD 1000000
#define E_PP 1000000
#define E_SD 500000

__device__ __forceinline__ float bf2f(u16 u) {
  union { unsigned int i; float f; } c; c.i = ((unsigned int)u) << 16; return c.f;
}
__device__ __forceinline__ u16 f2bf(float f) {
  union { float f; unsigned int i; } c; c.f = f;
  unsigned int u = c.i;
  unsigned int r = (u + 0x7fffu + ((u >> 16) & 1u)) >> 16;
  return (u16)r;
}

// ---------------------------------------------------------------------------
// Input dtype detection (worked in R3): for fp32 data, even u16s are mantissa
// halves (~16% sane exponent); for bf16 data ~100%.
// ---------------------------------------------------------------------------
__global__ void k_detect(const void* x, int* flag) {
  if (threadIdx.x == 0 && blockIdx.x == 0) {
    const u16* p = (const u16*)x;
    int sane = 0;
    for (int i = 0; i < 256; ++i) {
      const u16 v = p[2 * i];
      const int e = (v >> 7) & 0xff;
      sane += (e >= 100 && e <= 140) ? 1 : 0;
    }
    *flag = (sane >= 200) ? 1 : 0;   // 1 = bf16, 0 = fp32
  }
}

__device__ __forceinline__ float ld_in(const void* p, int i, int isbf) {
  return isbf ? bf2f(((const u16*)p)[i]) : ((const float*)p)[i];
}

// ---------------------------------------------------------------------------
// z = x @ W (per-node GEMV vs LDS-staged W). Optional: z_out bf16,
// el = sum_d(z*al) per head, er = sum_d(z*ar) per head.
// ---------------------------------------------------------------------------
__global__ __launch_bounds__(256) void k_transform(
    const void* __restrict__ x, const void* __restrict__ W,
    const void* __restrict__ al, const void* __restrict__ ar,
    u16* __restrict__ z_out, float* __restrict__ el_out, float* __restrict__ er_out,
    int N, const int* __restrict__ flagp)
{
  __shared__ u16 Ws[16384];
  __shared__ float xs[2][128];
  __shared__ float alS[128], arS[128];
  const int tid = threadIdx.x;
  const int sub = tid >> 7;
  const int j = tid & 127;
  const int isbf = *flagp;

  if (isbf) {
    uint4* dst4 = (uint4*)Ws;
    const uint4* src4 = (const uint4*)W;
    for (int i = tid; i < 2048; i += 256) dst4[i] = src4[i];
  } else {
    const float* Wf = (const float*)W;
    for (int i = tid; i < 16384; i += 256) Ws[i] = f2bf(Wf[i]);
  }
  if (tid < 128) {
    alS[tid] = al ? ld_in(al, tid, isbf) : 0.f;
    arS[tid] = ar ? ld_in(ar, tid, isbf) : 0.f;
  }
  __syncthreads();

  const bool has_al = (al != nullptr);
  const bool has_ar = (ar != nullptr);
  const bool has_z  = (z_out != nullptr);

  for (int n0 = blockIdx.x * 2; n0 < N; n0 += gridDim.x * 2) {
    const int n = n0 + sub;
    const bool act = (n < N);
    if (act) xs[sub][j] = ld_in(x, n * 128 + j, isbf);
    __syncthreads();

    float acc = 0.f;
    #pragma unroll 8
    for (int k = 0; k < 128; ++k)
      acc = fmaf(xs[sub][k], bf2f(Ws[k * 128 + j]), acc);

    if (act && has_z) z_out[n * 128 + j] = f2bf(acc);

    if (has_al) {
      float p = acc * alS[j];
      p += __shfl_xor(p, 1); p += __shfl_xor(p, 2);
      p += __shfl_xor(p, 4); p += __shfl_xor(p, 8);
      if (act && (j & 15) == 0) el_out[n * 8 + (j >> 4)] = p;
    }
    if (has_ar) {
      float p = acc * arS[j];
      p += __shfl_xor(p, 1); p += __shfl_xor(p, 2);
      p += __shfl_xor(p, 4); p += __shfl_xor(p, 8);
      if (act && (j & 15) == 0) er_out[n * 8 + (j >> 4)] = p;
    }
    __syncthreads();
  }
}

// ---------------------------------------------------------------------------
// CSR build step 1: counts[dst[e]]++  (int atomics on 120 KB, L2-resident)
// ---------------------------------------------------------------------------
__global__ __launch_bounds__(256) void k_count(
    const int* __restrict__ dst, int* __restrict__ counts, int E)
{
  const int e = blockIdx.x * 256 + threadIdx.x;
  if (e < E) atomicAdd(&counts[dst[e]], 1);
}

// ---------------------------------------------------------------------------
// CSR build step 2: exclusive prefix sum of counts -> offsets[0..n]
// Single block of 1024 threads, Hillis-Steele over per-thread chunk sums.
// ---------------------------------------------------------------------------
__global__ __launch_bounds__(1024) void k_scan(
    const int* __restrict__ counts, int* __restrict__ offsets, int n)
{
  __shared__ int tsum[1024];
  const int tid = threadIdx.x;
  const int chunk = (n + 1023) >> 10;
  const int base = tid * chunk;
  int sum = 0;
  for (int i = 0; i < chunk; ++i) {
    const int idx = base + i;
    if (idx < n) sum += counts[idx];
  }
  tsum[tid] = sum;
  __syncthreads();
  for (int off = 1; off < 1024; off <<= 1) {
    const int v = (tid >= off) ? tsum[tid - off] : 0;
    __syncthreads();
    tsum[tid] += v;
    __syncthreads();
  }
  int run = (tid == 0) ? 0 : tsum[tid - 1];
  for (int i = 0; i < chunk; ++i) {
    const int idx = base + i;
    if (idx < n) { offsets[idx] = run; run += counts[idx]; }
  }
  if (tid == 1023) offsets[n] = tsum[1023];
}

// ---------------------------------------------------------------------------
// CSR build step 3: scatter src ids. Uses counts as a down-cursor
// (atomicSub), so no separate cursor buffer / extra memset.
// ---------------------------------------------------------------------------
__global__ __launch_bounds__(256) void k_fill(
    const int* __restrict__ src, const int* __restrict__ dst,
    const int* __restrict__ offsets, int* __restrict__ counts,
    int* __restrict__ csr_src, int E)
{
  const int e = blockIdx.x * 256 + threadIdx.x;
  if (e >= E) return;
  const int d = dst[e];
  const int pos = atomicSub(&counts[d], 1) - 1;
  csr_src[offsets[d] + pos] = src[e];
}

// ---------------------------------------------------------------------------
// Aggregation: one wave per dst node. 64 lanes hold the 128-float
// accumulator (2/lane). Per edge: ex = exp(leakyrelu(el[s]+er[d])) per head,
// acc += ex * z[s]. Epilogue fuses finalize: feats = acc/den + b (bf16).
// No atomics anywhere.
// ---------------------------------------------------------------------------
__global__ __launch_bounds__(256) void k_aggregate(
    const int* __restrict__ csr_src, const int* __restrict__ offsets,
    const float* __restrict__ el, const float* __restrict__ er,
    const u16* __restrict__ z, const void* __restrict__ b,
    u16* __restrict__ feats, int rowStride, int N,
    const int* __restrict__ flagp)
{
  const int wave = (blockIdx.x * 256 + threadIdx.x) >> 6;
  const int lane = threadIdx.x & 63;
  if (wave >= N) return;
  const int d = wave;
  const int h = lane >> 3;            // head of this lane's 2 features
  const float erh = er[d * 8 + h];
  const int beg = offsets[d];
  const int end = offsets[d + 1];

  float acc0 = 0.f, acc1 = 0.f, den = 0.f;
  for (int p = beg; p < end; ++p) {
    const int s = csr_src[p];         // wave-uniform load
    float eh = el[s * 8 + h] + erh;
    eh = (eh >= 0.f) ? eh : 0.2f * eh;
    eh = fminf(eh, 60.f);
    const float ex = __expf(eh);
    den += ex;
    const unsigned int zp = *(const unsigned int*)(z + s * 128 + lane * 2);
    acc0 = fmaf(ex, bf2f((u16)(zp & 0xffffu)), acc0);
    acc1 = fmaf(ex, bf2f((u16)(zp >> 16)), acc1);
  }
  const float inv = 1.f / fmaxf(den, 1e-9f);
  const int isbf = *flagp;
  const int j0 = lane * 2;
  const float v0 = acc0 * inv + ld_in(b, j0, isbf);
  const float v1 = acc1 * inv + ld_in(b, j0 + 1, isbf);
  const unsigned int packed = (unsigned int)f2bf(v0) | ((unsigned int)f2bf(v1) << 16);
  *(unsigned int*)(feats + d * rowStride + j0) = packed;
}

// ---------------------------------------------------------------------------
// Semantic score: s[row] = tanh(f_row @ W1 + b1) @ W2 + b2, rows = N*R bf16
// ---------------------------------------------------------------------------
__global__ __launch_bounds__(256) void k_sem_score(
    const u16* __restrict__ f,
    const void* __restrict__ W1, const void* __restrict__ b1,
    const void* __restrict__ W2, const void* __restrict__ b2,
    float* __restrict__ s_out, int total, const int* __restrict__ flagp)
{
  __shared__ u16 W1s[16384];
  __shared__ float xs[2][128];
  __shared__ float b1S[128], W2S[128];
  __shared__ float wsum[2][2];
  const int tid = threadIdx.x;
  const int sub = tid >> 7;
  const int j = tid & 127;
  const int isbf = *flagp;

  if (isbf) {
    uint4* dst4 = (uint4*)W1s;
    const uint4* src4 = (const uint4*)W1;
    for (int i = tid; i < 2048; i += 256) dst4[i] = src4[i];
  } else {
    const float* Wf = (const float*)W1;
    for (int i = tid; i < 16384; i += 256) W1s[i] = f2bf(Wf[i]);
  }
  if (tid < 128) { b1S[tid] = ld_in(b1, tid, isbf); W2S[tid] = ld_in(W2, tid, isbf); }
  __syncthreads();
  const float b2v = ld_in(b2, 0, isbf);

  for (int r0 = blockIdx.x * 2; r0 < total; r0 += gridDim.x * 2) {
    const int row = r0 + sub;
    const bool act = (row < total);
    if (act) xs[sub][j] = bf2f(f[row * 128 + j]);
    __syncthreads();

    float acc = b1S[j];
    #pragma unroll 8
    for (int k = 0; k < 128; ++k)
      acc = fmaf(xs[sub][k], bf2f(W1s[k * 128 + j]), acc);

    float p = tanhf(acc) * W2S[j];
    p += __shfl_xor(p, 1);  p += __shfl_xor(p, 2);  p += __shfl_xor(p, 4);
    p += __shfl_xor(p, 8);  p += __shfl_xor(p, 16); p += __shfl_xor(p, 32);
    const int lane = tid & 63;
    const int wv = (tid >> 6) & 1;
    if (lane == 0) wsum[sub][wv] = p;
    __syncthreads();
    if (act && j == 0) s_out[row] = wsum[sub][0] + wsum[sub][1] + b2v;
    __syncthreads();
  }
}

// ---------------------------------------------------------------------------
// Combine: softmax over R relation scores, weighted sum of bf16 feats.
// ---------------------------------------------------------------------------
__global__ __launch_bounds__(256) void k_combine(
    const u16* __restrict__ feats, const float* __restrict__ s,
    void* __restrict__ out, int outBase, int N, int R,
    const int* __restrict__ flagp)
{
  const int i = blockIdx.x * 256 + threadIdx.x;
  if (i >= N * 128) return;
  const int isbf = *flagp;
  const int n = i >> 7;
  const int j = i & 127;
  const float* sr = s + n * R;
  const float s0v = sr[0];
  const float s1v = sr[1];
  const float s2v = (R == 3) ? sr[2] : -3.4e38f;
  const float m = fmaxf(fmaxf(s0v, s1v), s2v);
  const float w0 = __expf(s0v - m);
  const float w1 = __expf(s1v - m);
  const float w2 = (R == 3) ? __expf(s2v - m) : 0.f;
  const float inv = 1.f / (w0 + w1 + w2);
  float acc = w0 * bf2f(feats[(n * R + 0) * 128 + j])
            + w1 * bf2f(feats[(n * R + 1) * 128 + j]);
  if (R == 3) acc += w2 * bf2f(feats[(n * R + 2) * 128 + j]);
  const float v = acc * inv;
  if (isbf) ((u16*)out)[outBase + i] = f2bf(v);
  else      ((float*)out)[outBase + i] = v;
}

extern "C" void kernel_launch(void* const* d_in, const int* in_sizes, int n_in,
                              void* d_out, int out_size, void* d_ws, size_t ws_size,
                              hipStream_t stream)
{
  (void)in_sizes; (void)n_in; (void)out_size; (void)ws_size;

  const void* h_drug = d_in[0];
  const void* h_prot = d_in[1];
  const void* h_se   = d_in[2];
  const void* W_dd = d_in[3];
  const void* al_dd = d_in[4];
  const void* ar_dd = d_in[5];
  const void* b_dd  = d_in[6];
  const void* W_dp = d_in[7];
  const void* al_dp = d_in[8];
  const void* ar_dp = d_in[9];
  const void* b_dp  = d_in[10];
  const void* W_pd = d_in[11];
  const void* al_pd = d_in[12];
  const void* ar_pd = d_in[13];
  const void* b_pd  = d_in[14];
  const void* W_pp = d_in[15];
  const void* al_pp = d_in[16];
  const void* ar_pp = d_in[17];
  const void* b_pp  = d_in[18];
  const void* W_sd = d_in[19];
  const void* al_sd = d_in[20];
  const void* ar_sd = d_in[21];
  const void* b_sd  = d_in[22];
  const void* W1 = d_in[23];
  const void* b1 = d_in[24];
  const void* W2 = d_in[25];
  const void* b2 = d_in[26];
  const int* src_dd = (const int*)d_in[27];
  const int* dst_dd = (const int*)d_in[28];
  const int* src_dp = (const int*)d_in[29];
  const int* dst_dp = (const int*)d_in[30];
  const int* src_pd = (const int*)d_in[31];
  const int* dst_pd = (const int*)d_in[32];
  const int* src_pp = (const int*)d_in[33];
  const int* dst_pp = (const int*)d_in[34];
  const int* src_sd = (const int*)d_in[35];
  const int* dst_sd = (const int*)d_in[36];

  // ---- workspace layout (37,240,068 bytes) ----
  // el      fp32 [30000*8]     @ 0
  // er      fp32 [30000*8]     @ 960,000
  // z       bf16 [30000*128]   @ 1,920,000     (7.68 MB)
  // counts  int  [30000]       @ 9,600,000     (memset per relation)
  // offsets int  [30001]       @ 9,720,000     (pad to 120,064)
  // csr_src int  [1,000,000]   @ 9,840,064     (4 MB)
  // s       fp32 [90000]       @ 13,840,064
  // feats   bf16 [30000*3*128] @ 14,200,064    (23.04 MB)
  // flag    int                @ 37,240,064
  char* w = (char*)d_ws;
  float* el  = (float*)(w);
  float* er  = (float*)(w + 960000);
  u16*   z   = (u16*)  (w + 1920000);
  int* counts  = (int*)(w + 9600000);
  int* offsets = (int*)(w + 9720000);
  int* csr_src = (int*)(w + 9840064);
  float* s   = (float*)(w + 13840064);
  u16*   feats = (u16*)(w + 14200064);
  int*   flag  = (int*) (w + 37240064);

  const dim3 blk(256);
  auto tg = [](int N) { int g = (N + 1) / 2; return dim3(g < 2048 ? g : 2048); };
  auto cg = [](int E) { return dim3((E + 255) / 256); };
  auto ng = [](int N) { return dim3((N * 128 + 255) / 256); };
  const dim3 ag((30000 + 3) / 4);   // one wave per dst node, 4 waves/block

  k_detect<<<dim3(1), dim3(64), 0, stream>>>(h_drug, flag);

  // helper macro-ish lambda: build CSR for a relation
  auto build_csr = [&](const int* srcA, const int* dstA, int E) {
    (void)hipMemsetAsync(counts, 0, 120000, stream);
    k_count<<<cg(E), blk, 0, stream>>>(dstA, counts, E);
    k_scan<<<dim3(1), dim3(1024), 0, stream>>>(counts, offsets, 30000);
    k_fill<<<cg(E), blk, 0, stream>>>(srcA, dstA, offsets, counts, csr_src, E);
  };

  // ================= DRUG PHASE (relations dd, pd, sd; R=3) =================
  // --- dd (r=0) ---
  build_csr(src_dd, dst_dd, E_DD);
  k_transform<<<tg(ND), blk, 0, stream>>>(h_drug, W_dd, al_dd, ar_dd, z, el, er, ND, flag);
  k_aggregate<<<ag, blk, 0, stream>>>(csr_src, offsets, el, er, z, b_dd, feats + 0 * 128, 384, ND, flag);
  // --- pd (r=1) ---
  build_csr(src_pd, dst_pd, E_PD);
  k_transform<<<tg(NP), blk, 0, stream>>>(h_prot, W_pd, al_pd, nullptr, z, el, nullptr, NP, flag);
  k_transform<<<tg(ND), blk, 0, stream>>>(h_drug, W_pd, nullptr, ar_pd, nullptr, nullptr, er, ND, flag);
  k_aggregate<<<ag, blk, 0, stream>>>(csr_src, offsets, el, er, z, b_pd, feats + 1 * 128, 384, ND, flag);
  // --- sd (r=2) ---
  build_csr(src_sd, dst_sd, E_SD);
  k_transform<<<tg(NS), blk, 0, stream>>>(h_se, W_sd, al_sd, nullptr, z, el, nullptr, NS, flag);
  k_transform<<<tg(ND), blk, 0, stream>>>(h_drug, W_sd, nullptr, ar_sd, nullptr, nullptr, er, ND, flag);
  k_aggregate<<<ag, blk, 0, stream>>>(csr_src, offsets, el, er, z, b_sd, feats + 2 * 128, 384, ND, flag);
  // --- semantic + combine ---
  k_sem_score<<<dim3(2048), blk, 0, stream>>>(feats, W1, b1, W2, b2, s, ND * 3, flag);
  k_combine<<<ng(ND), blk, 0, stream>>>(feats, s, d_out, 0, ND, 3, flag);

  // ================ PROTEIN PHASE (relations dp, pp; R=2) ====================
  // --- dp (r=0) ---
  build_csr(src_dp, dst_dp, E_DP);
  k_transform<<<tg(ND), blk, 0, stream>>>(h_drug, W_dp, al_dp, nullptr, z, el, nullptr, ND, flag);
  k_transform<<<tg(NP), blk, 0, stream>>>(h_prot, W_dp, nullptr, ar_dp, nullptr, nullptr, er, NP, flag);
  k_aggregate<<<ag, blk, 0, stream>>>(csr_src, offsets, el, er, z, b_dp, feats + 0 * 128, 256, NP, flag);
  // --- pp (r=1) ---
  build_csr(src_pp, dst_pp, E_PP);
  k_transform<<<tg(NP), blk, 0, stream>>>(h_prot, W_pp, al_pp, ar_pp, z, el, er, NP, flag);
  k_aggregate<<<ag, blk, 0, stream>>>(csr_src, offsets, el, er, z, b_pp, feats + 1 * 128, 256, NP, flag);
  // --- semantic + combine ---
  k_sem_score<<<dim3(2048), blk, 0, stream>>>(feats, W1, b1, W2, b2, s, NP * 2, flag);
  k_combine<<<ng(NP), blk, 0, stream>>>(feats, s, d_out, ND * 128, NP, 2, flag);
}

// Round 5
// 1515.225 us; speedup vs baseline: 11.1931x; 1.3527x over previous
//
#include <hip/hip_runtime.h>
#include <hip/hip_bf16.h>

typedef unsigned short u16;
typedef __attribute__((ext_vector_type(8))) short short8;   // 8 bf16 (4 VGPRs)
typedef __attribute__((ext_vector_type(4))) float f32x4;

#define ND 30000
#define NP 30000
#define NS 10000
#define E_DD 1000000
#define E_DP 1000000
#define E_PD 1000000
#define E_PP 1000000
#define E_SD 500000

__device__ __forceinline__ float bf2f(u16 u) {
  union { unsigned int i; float f; } c; c.i = ((unsigned int)u) << 16; return c.f;
}
__device__ __forceinline__ u16 f2bf(float f) {
  union { float f; unsigned int i; } c; c.f = f;
  unsigned int u = c.i;
  unsigned int r = (u + 0x7fffu + ((u >> 16) & 1u)) >> 16;
  return (u16)r;
}

// ---------------------------------------------------------------------------
// Input dtype detection (proven in R3/R4).
// ---------------------------------------------------------------------------
__global__ void k_detect(const void* x, int* flag) {
  if (threadIdx.x == 0 && blockIdx.x == 0) {
    const u16* p = (const u16*)x;
    int sane = 0;
    for (int i = 0; i < 256; ++i) {
      const u16 v = p[2 * i];
      const int e = (v >> 7) & 0xff;
      sane += (e >= 100 && e <= 140) ? 1 : 0;
    }
    *flag = (sane >= 200) ? 1 : 0;   // 1 = bf16, 0 = fp32
  }
}

__device__ __forceinline__ float ld_in(const void* p, int i, int isbf) {
  return isbf ? bf2f(((const u16*)p)[i]) : ((const float*)p)[i];
}

// ---------------------------------------------------------------------------
// Wal[h][k] = sum_d W[k][h*16+d]*al[h*16+d]  (and War with ar).
// Folds el/er computation into the transform GEMM as extra B columns.
// ---------------------------------------------------------------------------
__global__ void k_prep(const void* __restrict__ W, const void* __restrict__ al,
                       const void* __restrict__ ar, float* __restrict__ wal,
                       float* __restrict__ war, const int* __restrict__ flagp)
{
  const int k = threadIdx.x;  // 128 threads
  const int isbf = *flagp;
  for (int h = 0; h < 8; ++h) {
    float sa = 0.f, sr = 0.f;
    for (int d = 0; d < 16; ++d) {
      const float wv = ld_in(W, k * 128 + h * 16 + d, isbf);
      sa = fmaf(wv, ld_in(al, h * 16 + d, isbf), sa);
      sr = fmaf(wv, ld_in(ar, h * 16 + d, isbf), sr);
    }
    wal[h * 128 + k] = sa;
    war[h * 128 + k] = sr;
  }
}

// ---------------------------------------------------------------------------
// MFMA transform: [N x 128] @ [128 x 144] where cols 0..127 = W (-> z bf16),
// 128..135 = Wal (-> el), 136..143 = War (-> er). T0=0: full; T0=8: el/er only.
// Block 256 = 4 waves, 64 rows/block. B frag-order LDS layout gives b128 reads.
// ---------------------------------------------------------------------------
template<int T0>
__global__ __launch_bounds__(256) void k_xform(
    const void* __restrict__ x, const void* __restrict__ W,
    const float* __restrict__ wal, const float* __restrict__ war,
    u16* __restrict__ z_out, float* __restrict__ el_out, float* __restrict__ er_out,
    int N, const int* __restrict__ flagp)
{
  __shared__ __align__(16) u16 Bf[4 * 144 * 32];   // [kc][n][q][j], 36,864 B
  __shared__ __align__(16) u16 As[64 * 136];       // 64 rows, pad 136, 17,408 B
  const int tid = threadIdx.x;
  const int isbf = *flagp;
  const int row0 = blockIdx.x * 64;

  // ---- stage B fragments ----
  if (T0 == 0) {
    for (int i = tid; i < 18432; i += 256) {        // identity layout: Bf[i]
      const int kc = i / 4608;
      const int rem = i - kc * 4608;
      const int n = rem >> 5;
      const int q = (rem >> 3) & 3, j = rem & 7;
      const int k = kc * 32 + q * 8 + j;
      float v;
      if (n < 128) v = ld_in(W, k * 128 + n, isbf);
      else if (n < 136) v = wal[(n - 128) * 128 + k];
      else v = war[(n - 136) * 128 + k];
      Bf[i] = f2bf(v);
    }
  } else {
    for (int i = tid; i < 2048; i += 256) {         // tile 8 only
      const int kc = i >> 9;
      const int rem = i & 511;
      const int n = 128 + (rem >> 5);
      const int q = (rem >> 3) & 3, j = rem & 7;
      const int k = kc * 32 + q * 8 + j;
      const float v = (n < 136) ? wal[(n - 128) * 128 + k] : war[(n - 136) * 128 + k];
      Bf[((kc * 144 + n) * 4 + q) * 8 + j] = f2bf(v);
    }
  }

  // ---- stage A tile (64 x 128 bf16, rows padded to 136) ----
  if (isbf) {
    const uint4* xv = (const uint4*)x;
    for (int i = tid; i < 1024; i += 256) {
      const int r = i >> 4, c8 = i & 15;
      const int row = row0 + r;
      uint4 v = make_uint4(0, 0, 0, 0);
      if (row < N) v = xv[row * 16 + c8];
      *(uint4*)&As[r * 136 + c8 * 8] = v;
    }
  } else {
    const float4* xf = (const float4*)x;
    for (int i = tid; i < 2048; i += 256) {
      const int r = i >> 5, c4 = i & 31;
      const int row = row0 + r;
      unsigned long long pk = 0ull;
      if (row < N) {
        const float4 v = xf[row * 32 + c4];
        pk = (unsigned long long)f2bf(v.x) | ((unsigned long long)f2bf(v.y) << 16)
           | ((unsigned long long)f2bf(v.z) << 32) | ((unsigned long long)f2bf(v.w) << 48);
      }
      *(unsigned long long*)&As[r * 136 + c4 * 4] = pk;
    }
  }
  __syncthreads();

  // ---- MFMA K-loop ----
  const int wave = tid >> 6;
  const int lane = tid & 63;
  const int q = lane >> 4;
  const int c = lane & 15;

  f32x4 acc[9];
  #pragma unroll
  for (int t = T0; t < 9; ++t) acc[t] = (f32x4){0.f, 0.f, 0.f, 0.f};

  #pragma unroll
  for (int kc = 0; kc < 4; ++kc) {
    const short8 a = *(const short8*)&As[(wave * 16 + c) * 136 + kc * 32 + q * 8];
    #pragma unroll
    for (int t = T0; t < 9; ++t) {
      const short8 b = *(const short8*)&Bf[((kc * 144 + t * 16 + c) * 4 + q) * 8];
      acc[t] = __builtin_amdgcn_mfma_f32_16x16x32_bf16(a, b, acc[t], 0, 0, 0);
    }
  }

  // ---- epilogue: D row = q*4+r, col = t*16+c ----
  const int rbase = row0 + wave * 16 + q * 4;
  if (T0 == 0 && z_out) {
    #pragma unroll
    for (int t = 0; t < 8; ++t)
      #pragma unroll
      for (int r = 0; r < 4; ++r) {
        const int row = rbase + r;
        if (row < N) z_out[row * 128 + t * 16 + c] = f2bf(acc[t][r]);
      }
  }
  #pragma unroll
  for (int r = 0; r < 4; ++r) {
    const int row = rbase + r;
    if (row < N) {
      const float v = acc[8][r];
      if (c < 8) { if (el_out) el_out[row * 8 + c] = v; }
      else       { if (er_out) er_out[row * 8 + (c - 8)] = v; }
    }
  }
}

// ---------------------------------------------------------------------------
// CSR build (proven in R4): count -> scan -> fill.
// ---------------------------------------------------------------------------
__global__ __launch_bounds__(256) void k_count(
    const int* __restrict__ dst, int* __restrict__ counts, int E)
{
  const int e = blockIdx.x * 256 + threadIdx.x;
  if (e < E) atomicAdd(&counts[dst[e]], 1);
}

__global__ __launch_bounds__(1024) void k_scan(
    const int* __restrict__ counts, int* __restrict__ offsets, int n)
{
  __shared__ int tsum[1024];
  const int tid = threadIdx.x;
  const int chunk = (n + 1023) >> 10;
  const int base = tid * chunk;
  int sum = 0;
  for (int i = 0; i < chunk; ++i) {
    const int idx = base + i;
    if (idx < n) sum += counts[idx];
  }
  tsum[tid] = sum;
  __syncthreads();
  for (int off = 1; off < 1024; off <<= 1) {
    const int v = (tid >= off) ? tsum[tid - off] : 0;
    __syncthreads();
    tsum[tid] += v;
    __syncthreads();
  }
  int run = (tid == 0) ? 0 : tsum[tid - 1];
  for (int i = 0; i < chunk; ++i) {
    const int idx = base + i;
    if (idx < n) { offsets[idx] = run; run += counts[idx]; }
  }
  if (tid == 1023) offsets[n] = tsum[1023];
}

__global__ __launch_bounds__(256) void k_fill(
    const int* __restrict__ src, const int* __restrict__ dst,
    const int* __restrict__ offsets, int* __restrict__ counts,
    int* __restrict__ csr_src, int E)
{
  const int e = blockIdx.x * 256 + threadIdx.x;
  if (e >= E) return;
  const int d = dst[e];
  const int pos = atomicSub(&counts[d], 1) - 1;
  csr_src[offsets[d] + pos] = src[e];
}

// ---------------------------------------------------------------------------
// Aggregation (proven in R4, + 2-edge unroll for load ILP).
// ---------------------------------------------------------------------------
__global__ __launch_bounds__(256) void k_aggregate(
    const int* __restrict__ csr_src, const int* __restrict__ offsets,
    const float* __restrict__ el, const float* __restrict__ er,
    const u16* __restrict__ z, const void* __restrict__ b,
    u16* __restrict__ feats, int rowStride, int N,
    const int* __restrict__ flagp)
{
  const int wave = (blockIdx.x * 256 + threadIdx.x) >> 6;
  const int lane = threadIdx.x & 63;
  if (wave >= N) return;
  const int d = wave;
  const int h = lane >> 3;
  const float erh = er[d * 8 + h];
  const int beg = offsets[d];
  const int end = offsets[d + 1];

  float acc0 = 0.f, acc1 = 0.f, den = 0.f;
  int p = beg;
  for (; p + 2 <= end; p += 2) {
    const int s0 = csr_src[p];
    const int s1 = csr_src[p + 1];
    float eh0 = el[s0 * 8 + h] + erh;
    float eh1 = el[s1 * 8 + h] + erh;
    const unsigned int zp0 = *(const unsigned int*)(z + s0 * 128 + lane * 2);
    const unsigned int zp1 = *(const unsigned int*)(z + s1 * 128 + lane * 2);
    eh0 = (eh0 >= 0.f) ? eh0 : 0.2f * eh0;  eh0 = fminf(eh0, 60.f);
    eh1 = (eh1 >= 0.f) ? eh1 : 0.2f * eh1;  eh1 = fminf(eh1, 60.f);
    const float ex0 = __expf(eh0);
    const float ex1 = __expf(eh1);
    den += ex0 + ex1;
    acc0 = fmaf(ex0, bf2f((u16)(zp0 & 0xffffu)), acc0);
    acc1 = fmaf(ex0, bf2f((u16)(zp0 >> 16)), acc1);
    acc0 = fmaf(ex1, bf2f((u16)(zp1 & 0xffffu)), acc0);
    acc1 = fmaf(ex1, bf2f((u16)(zp1 >> 16)), acc1);
  }
  if (p < end) {
    const int s0 = csr_src[p];
    float eh0 = el[s0 * 8 + h] + erh;
    eh0 = (eh0 >= 0.f) ? eh0 : 0.2f * eh0;  eh0 = fminf(eh0, 60.f);
    const float ex0 = __expf(eh0);
    const unsigned int zp0 = *(const unsigned int*)(z + s0 * 128 + lane * 2);
    den += ex0;
    acc0 = fmaf(ex0, bf2f((u16)(zp0 & 0xffffu)), acc0);
    acc1 = fmaf(ex0, bf2f((u16)(zp0 >> 16)), acc1);
  }
  const float inv = 1.f / fmaxf(den, 1e-9f);
  const int isbf = *flagp;
  const int j0 = lane * 2;
  const float v0 = acc0 * inv + ld_in(b, j0, isbf);
  const float v1 = acc1 * inv + ld_in(b, j0 + 1, isbf);
  const unsigned int packed = (unsigned int)f2bf(v0) | ((unsigned int)f2bf(v1) << 16);
  *(unsigned int*)(feats + d * rowStride + j0) = packed;
}

// ---------------------------------------------------------------------------
// MFMA semantic score: s[row] = tanh(f_row @ W1 + b1) . W2 + b2.
// Same GEMM skeleton as k_xform; epilogue does tanh + quad reduction.
// ---------------------------------------------------------------------------
__global__ __launch_bounds__(256) void k_sem(
    const u16* __restrict__ f,
    const void* __restrict__ W1, const void* __restrict__ b1,
    const void* __restrict__ W2, const void* __restrict__ b2,
    float* __restrict__ s_out, int total, const int* __restrict__ flagp)
{
  __shared__ __align__(16) u16 Bf[4 * 128 * 32];   // 32,768 B
  __shared__ __align__(16) u16 As[64 * 136];       // 17,408 B
  __shared__ float b1S[128], W2S[128];
  const int tid = threadIdx.x;
  const int isbf = *flagp;
  const int row0 = blockIdx.x * 64;

  for (int i = tid; i < 16384; i += 256) {          // identity frag layout
    const int kc = i >> 12;
    const int rem = i & 4095;
    const int n = rem >> 5;
    const int q = (rem >> 3) & 3, j = rem & 7;
    const int k = kc * 32 + q * 8 + j;
    Bf[i] = f2bf(ld_in(W1, k * 128 + n, isbf));
  }
  if (tid < 128) { b1S[tid] = ld_in(b1, tid, isbf); W2S[tid] = ld_in(W2, tid, isbf); }

  {
    const uint4* xv = (const uint4*)f;
    for (int i = tid; i < 1024; i += 256) {
      const int r = i >> 4, c8 = i & 15;
      const int row = row0 + r;
      uint4 v = make_uint4(0, 0, 0, 0);
      if (row < total) v = xv[row * 16 + c8];
      *(uint4*)&As[r * 136 + c8 * 8] = v;
    }
  }
  __syncthreads();

  const int wave = tid >> 6;
  const int lane = tid & 63;
  const int q = lane >> 4;
  const int c = lane & 15;

  f32x4 acc[8];
  #pragma unroll
  for (int t = 0; t < 8; ++t) acc[t] = (f32x4){0.f, 0.f, 0.f, 0.f};

  #pragma unroll
  for (int kc = 0; kc < 4; ++kc) {
    const short8 a = *(const short8*)&As[(wave * 16 + c) * 136 + kc * 32 + q * 8];
    #pragma unroll
    for (int t = 0; t < 8; ++t) {
      const short8 b = *(const short8*)&Bf[((kc * 128 + t * 16 + c) * 4 + q) * 8];
      acc[t] = __builtin_amdgcn_mfma_f32_16x16x32_bf16(a, b, acc[t], 0, 0, 0);
    }
  }

  float part[4] = {0.f, 0.f, 0.f, 0.f};
  #pragma unroll
  for (int t = 0; t < 8; ++t) {
    const int n = t * 16 + c;
    const float b1v = b1S[n];
    const float w2v = W2S[n];
    #pragma unroll
    for (int r = 0; r < 4; ++r) {
      const float hv = acc[t][r] + b1v;
      const float e = __expf(2.f * hv);
      const float th = 1.f - 2.f / (e + 1.f);   // tanh, overflow-safe
      part[r] = fmaf(th, w2v, part[r]);
    }
  }
  #pragma unroll
  for (int r = 0; r < 4; ++r) {
    part[r] += __shfl_xor(part[r], 1);
    part[r] += __shfl_xor(part[r], 2);
    part[r] += __shfl_xor(part[r], 4);
    part[r] += __shfl_xor(part[r], 8);
  }
  if (c == 0) {
    const float b2v = ld_in(b2, 0, isbf);
    #pragma unroll
    for (int r = 0; r < 4; ++r) {
      const int row = row0 + wave * 16 + q * 4 + r;
      if (row < total) s_out[row] = part[r] + b2v;
    }
  }
}

// ---------------------------------------------------------------------------
// Combine: softmax over R relation scores, weighted sum of bf16 feats.
// ---------------------------------------------------------------------------
__global__ __launch_bounds__(256) void k_combine(
    const u16* __restrict__ feats, const float* __restrict__ s,
    void* __restrict__ out, int outBase, int N, int R,
    const int* __restrict__ flagp)
{
  const int i = blockIdx.x * 256 + threadIdx.x;
  if (i >= N * 128) return;
  const int isbf = *flagp;
  const int n = i >> 7;
  const int j = i & 127;
  const float* sr = s + n * R;
  const float s0v = sr[0];
  const float s1v = sr[1];
  const float s2v = (R == 3) ? sr[2] : -3.4e38f;
  const float m = fmaxf(fmaxf(s0v, s1v), s2v);
  const float w0 = __expf(s0v - m);
  const float w1 = __expf(s1v - m);
  const float w2 = (R == 3) ? __expf(s2v - m) : 0.f;
  const float inv = 1.f / (w0 + w1 + w2);
  float acc = w0 * bf2f(feats[(n * R + 0) * 128 + j])
            + w1 * bf2f(feats[(n * R + 1) * 128 + j]);
  if (R == 3) acc += w2 * bf2f(feats[(n * R + 2) * 128 + j]);
  const float v = acc * inv;
  if (isbf) ((u16*)out)[outBase + i] = f2bf(v);
  else      ((float*)out)[outBase + i] = v;
}

extern "C" void kernel_launch(void* const* d_in, const int* in_sizes, int n_in,
                              void* d_out, int out_size, void* d_ws, size_t ws_size,
                              hipStream_t stream)
{
  (void)in_sizes; (void)n_in; (void)out_size; (void)ws_size;

  const void* h_drug = d_in[0];
  const void* h_prot = d_in[1];
  const void* h_se   = d_in[2];
  const void* W_dd = d_in[3];
  const void* al_dd = d_in[4];
  const void* ar_dd = d_in[5];
  const void* b_dd  = d_in[6];
  const void* W_dp = d_in[7];
  const void* al_dp = d_in[8];
  const void* ar_dp = d_in[9];
  const void* b_dp  = d_in[10];
  const void* W_pd = d_in[11];
  const void* al_pd = d_in[12];
  const void* ar_pd = d_in[13];
  const void* b_pd  = d_in[14];
  const void* W_pp = d_in[15];
  const void* al_pp = d_in[16];
  const void* ar_pp = d_in[17];
  const void* b_pp  = d_in[18];
  const void* W_sd = d_in[19];
  const void* al_sd = d_in[20];
  const void* ar_sd = d_in[21];
  const void* b_sd  = d_in[22];
  const void* W1 = d_in[23];
  const void* b1 = d_in[24];
  const void* W2 = d_in[25];
  const void* b2 = d_in[26];
  const int* src_dd = (const int*)d_in[27];
  const int* dst_dd = (const int*)d_in[28];
  const int* src_dp = (const int*)d_in[29];
  const int* dst_dp = (const int*)d_in[30];
  const int* src_pd = (const int*)d_in[31];
  const int* dst_pd = (const int*)d_in[32];
  const int* src_pp = (const int*)d_in[33];
  const int* dst_pp = (const int*)d_in[34];
  const int* src_sd = (const int*)d_in[35];
  const int* dst_sd = (const int*)d_in[36];

  // ---- workspace layout (~37.3 MB, under proven 49.3 MB budget) ----
  char* w = (char*)d_ws;
  float* el  = (float*)(w);                    //  960,000
  float* er  = (float*)(w + 960000);           //  960,000
  u16*   z   = (u16*)  (w + 1920000);          //  7,680,000
  int* counts  = (int*)(w + 9600000);          //  120,000
  int* offsets = (int*)(w + 9720000);          //  120,064
  int* csr_src = (int*)(w + 9840064);          //  4,000,000
  float* s   = (float*)(w + 13840064);         //  360,000
  u16*   feats = (u16*)(w + 14200064);         //  23,040,000
  int*   flag  = (int*) (w + 37240064);        //  16 (pad)
  float* ww    = (float*)(w + 37240080);       //  5 rel x (wal 4KB + war 4KB)
  float *wal_dd = ww,        *war_dd = ww + 1024,
        *wal_pd = ww + 2048, *war_pd = ww + 3072,
        *wal_sd = ww + 4096, *war_sd = ww + 5120,
        *wal_dp = ww + 6144, *war_dp = ww + 7168,
        *wal_pp = ww + 8192, *war_pp = ww + 9216;

  const dim3 blk(256);
  auto cg = [](int E) { return dim3((E + 255) / 256); };
  auto xg = [](int N) { return dim3((N + 63) / 64); };
  auto ng = [](int N) { return dim3((N * 128 + 255) / 256); };
  const dim3 ag((30000 + 3) / 4);

  k_detect<<<dim3(1), dim3(64), 0, stream>>>(h_drug, flag);

  k_prep<<<dim3(1), dim3(128), 0, stream>>>(W_dd, al_dd, ar_dd, wal_dd, war_dd, flag);
  k_prep<<<dim3(1), dim3(128), 0, stream>>>(W_pd, al_pd, ar_pd, wal_pd, war_pd, flag);
  k_prep<<<dim3(1), dim3(128), 0, stream>>>(W_sd, al_sd, ar_sd, wal_sd, war_sd, flag);
  k_prep<<<dim3(1), dim3(128), 0, stream>>>(W_dp, al_dp, ar_dp, wal_dp, war_dp, flag);
  k_prep<<<dim3(1), dim3(128), 0, stream>>>(W_pp, al_pp, ar_pp, wal_pp, war_pp, flag);

  auto build_csr = [&](const int* srcA, const int* dstA, int E) {
    (void)hipMemsetAsync(counts, 0, 120000, stream);
    k_count<<<cg(E), blk, 0, stream>>>(dstA, counts, E);
    k_scan<<<dim3(1), dim3(1024), 0, stream>>>(counts, offsets, 30000);
    k_fill<<<cg(E), blk, 0, stream>>>(srcA, dstA, offsets, counts, csr_src, E);
  };

  // ================= DRUG PHASE (dd, pd, sd; R=3) =================
  build_csr(src_dd, dst_dd, E_DD);
  k_xform<0><<<xg(ND), blk, 0, stream>>>(h_drug, W_dd, wal_dd, war_dd, z, el, er, ND, flag);
  k_aggregate<<<ag, blk, 0, stream>>>(csr_src, offsets, el, er, z, b_dd, feats + 0 * 128, 384, ND, flag);

  build_csr(src_pd, dst_pd, E_PD);
  k_xform<0><<<xg(NP), blk, 0, stream>>>(h_prot, W_pd, wal_pd, war_pd, z, el, nullptr, NP, flag);
  k_xform<8><<<xg(ND), blk, 0, stream>>>(h_drug, W_pd, wal_pd, war_pd, nullptr, nullptr, er, ND, flag);
  k_aggregate<<<ag, blk, 0, stream>>>(csr_src, offsets, el, er, z, b_pd, feats + 1 * 128, 384, ND, flag);

  build_csr(src_sd, dst_sd, E_SD);
  k_xform<0><<<xg(NS), blk, 0, stream>>>(h_se, W_sd, wal_sd, war_sd, z, el, nullptr, NS, flag);
  k_xform<8><<<xg(ND), blk, 0, stream>>>(h_drug, W_sd, wal_sd, war_sd, nullptr, nullptr, er, ND, flag);
  k_aggregate<<<ag, blk, 0, stream>>>(csr_src, offsets, el, er, z, b_sd, feats + 2 * 128, 384, ND, flag);

  k_sem<<<xg(ND * 3), blk, 0, stream>>>(feats, W1, b1, W2, b2, s, ND * 3, flag);
  k_combine<<<ng(ND), blk, 0, stream>>>(feats, s, d_out, 0, ND, 3, flag);

  // ================ PROTEIN PHASE (dp, pp; R=2) ====================
  build_csr(src_dp, dst_dp, E_DP);
  k_xform<0><<<xg(ND), blk, 0, stream>>>(h_drug, W_dp, wal_dp, war_dp, z, el, nullptr, ND, flag);
  k_xform<8><<<xg(NP), blk, 0, stream>>>(h_prot, W_dp, wal_dp, war_dp, nullptr, nullptr, er, NP, flag);
  k_aggregate<<<ag, blk, 0, stream>>>(csr_src, offsets, el, er, z, b_dp, feats + 0 * 128, 256, NP, flag);

  build_csr(src_pp, dst_pp, E_PP);
  k_xform<0><<<xg(NP), blk, 0, stream>>>(h_prot, W_pp, wal_pp, war_pp, z, el, er, NP, flag);
  k_aggregate<<<ag, blk, 0, stream>>>(csr_src, offsets, el, er, z, b_pp, feats + 1 * 128, 256, NP, flag);

  k_sem<<<xg(NP * 2), blk, 0, stream>>>(feats, W1, b1, W2, b2, s, NP * 2, flag);
  k_combine<<<ng(NP), blk, 0, stream>>>(feats, s, d_out, ND * 128, NP, 2, flag);
}

// Round 6
// 948.244 us; speedup vs baseline: 17.8857x; 1.5979x over previous
//
#include <hip/hip_runtime.h>
#include <hip/hip_bf16.h>

typedef unsigned short u16;
typedef __attribute__((ext_vector_type(8))) short short8;   // 8 bf16 (4 VGPRs)
typedef __attribute__((ext_vector_type(4))) float f32x4;

#define ND 30000
#define NP 30000
#define NS 10000
#define NREL 5
#define CSTRIDE 30016          // counts/offsets per-relation stride (ints)
#define ETOT 4500000

__device__ __forceinline__ float bf2f(u16 u) {
  union { unsigned int i; float f; } c; c.i = ((unsigned int)u) << 16; return c.f;
}
__device__ __forceinline__ u16 f2bf(float f) {
  union { float f; unsigned int i; } c; c.f = f;
  unsigned int u = c.i;
  unsigned int r = (u + 0x7fffu + ((u >> 16) & 1u)) >> 16;
  return (u16)r;
}

__global__ void k_detect(const void* x, int* flag) {
  if (threadIdx.x == 0 && blockIdx.x == 0) {
    const u16* p = (const u16*)x;
    int sane = 0;
    for (int i = 0; i < 256; ++i) {
      const u16 v = p[2 * i];
      const int e = (v >> 7) & 0xff;
      sane += (e >= 100 && e <= 140) ? 1 : 0;
    }
    *flag = (sane >= 200) ? 1 : 0;   // 1 = bf16, 0 = fp32
  }
}

__device__ __forceinline__ float ld_in(const void* p, int i, int isbf) {
  return isbf ? bf2f(((const u16*)p)[i]) : ((const float*)p)[i];
}

// ---------------------------------------------------------------------------
// Wal[h][k] = sum_d W[k][h*16+d]*al[h*16+d] (and War). Block b = relation b.
// ---------------------------------------------------------------------------
struct PJobs { const void* W[5]; const void* al[5]; const void* ar[5];
               float* wal[5]; float* war[5]; };
__global__ __launch_bounds__(128) void k_prep_all(PJobs J, const int* flagp) {
  const int b = blockIdx.x;
  const int k = threadIdx.x;
  const int isbf = *flagp;
  for (int h = 0; h < 8; ++h) {
    float sa = 0.f, sr = 0.f;
    for (int d = 0; d < 16; ++d) {
      const float wv = ld_in(J.W[b], k * 128 + h * 16 + d, isbf);
      sa = fmaf(wv, ld_in(J.al[b], h * 16 + d, isbf), sa);
      sr = fmaf(wv, ld_in(J.ar[b], h * 16 + d, isbf), sr);
    }
    J.wal[b][h * 128 + k] = sa;
    J.war[b][h * 128 + k] = sr;
  }
}

// ---------------------------------------------------------------------------
// Pre-pack B into MFMA fragment order: pack[((kc*144+n)*4+q)*8+j] = B[k][n],
// k = kc*32+q*8+j. Jobs 0..4: W|Wal|War (144 cols). Job 5: W1 (cols>=128 -> 0).
// 9 blocks/job x 2048 elems.
// ---------------------------------------------------------------------------
struct KPack { const void* W[6]; const float* wal[6]; const float* war[6];
               u16* out[6]; };
__global__ __launch_bounds__(256) void k_pack_all(KPack J, const int* flagp) {
  const int job = blockIdx.x / 9;
  const int i0 = (blockIdx.x % 9) * 2048 + threadIdx.x * 8;
  const int isbf = *flagp;
  const int kc = i0 / 4608;
  const int rem = i0 - kc * 4608;
  const int n = rem >> 5;
  const int q = (rem >> 3) & 3;
  u16 vals[8];
  #pragma unroll
  for (int j = 0; j < 8; ++j) {
    const int k = kc * 32 + q * 8 + j;
    float v;
    if (job == 5)      v = (n < 128) ? ld_in(J.W[5], k * 128 + n, isbf) : 0.f;
    else if (n < 128)  v = ld_in(J.W[job], k * 128 + n, isbf);
    else if (n < 136)  v = J.wal[job][(n - 128) * 128 + k];
    else               v = J.war[job][(n - 136) * 128 + k];
    vals[j] = f2bf(v);
  }
  *(uint4*)&J.out[job][i0] = *(uint4*)vals;
}

// ---------------------------------------------------------------------------
// Batched MFMA transform: 8 jobs, [Nx128]@[128x144]; tiles 0..7 -> z (bf16),
// tile 8 -> el/er. t0=8 jobs compute only tile 8.
// ---------------------------------------------------------------------------
struct XJobs {
  const void* x[8]; const u16* bp[8]; u16* z[8]; float* el[8]; float* er[8];
  int N[8]; int t0[8]; int blk0[9];
};
__global__ __launch_bounds__(256) void k_xform_all(XJobs J, const int* flagp) {
  __shared__ __align__(16) u16 Bf[18432];
  __shared__ __align__(16) u16 As[64 * 136];
  const int tid = threadIdx.x;
  const int isbf = *flagp;

  int job = 0, b = blockIdx.x;
  while (b >= J.blk0[job + 1]) ++job;
  const int row0 = (b - J.blk0[job]) * 64;
  const int N = J.N[job];
  const int t0 = J.t0[job];
  const u16* bp = J.bp[job];
  const void* x = J.x[job];

  // ---- stage B (uint4 copies from pre-packed frags) ----
  if (t0 == 0) {
    for (int i = tid * 8; i < 18432; i += 2048)
      *(uint4*)&Bf[i] = *(const uint4*)&bp[i];
  } else {
    const int i = tid * 8;                    // 2048 elems = exactly 1/thread
    const int kc = i >> 9;
    const int off = (kc * 144 + 128) * 32 + (i & 511);
    *(uint4*)&Bf[off] = *(const uint4*)&bp[off];
  }

  // ---- stage A (64 x 128 bf16, row pad 136) ----
  if (isbf) {
    const uint4* xv = (const uint4*)x;
    for (int i = tid; i < 1024; i += 256) {
      const int r = i >> 4, c8 = i & 15;
      const int row = row0 + r;
      uint4 v = make_uint4(0, 0, 0, 0);
      if (row < N) v = xv[row * 16 + c8];
      *(uint4*)&As[r * 136 + c8 * 8] = v;
    }
  } else {
    const float4* xf = (const float4*)x;
    for (int i = tid; i < 2048; i += 256) {
      const int r = i >> 5, c4 = i & 31;
      const int row = row0 + r;
      unsigned long long pk = 0ull;
      if (row < N) {
        const float4 v = xf[row * 32 + c4];
        pk = (unsigned long long)f2bf(v.x) | ((unsigned long long)f2bf(v.y) << 16)
           | ((unsigned long long)f2bf(v.z) << 32) | ((unsigned long long)f2bf(v.w) << 48);
      }
      *(unsigned long long*)&As[r * 136 + c4 * 4] = pk;
    }
  }
  __syncthreads();

  const int wave = tid >> 6;
  const int lane = tid & 63;
  const int q = lane >> 4;
  const int c = lane & 15;

  f32x4 accT[8];
  f32x4 acc8 = (f32x4){0.f, 0.f, 0.f, 0.f};
  if (t0 == 0) {
    #pragma unroll
    for (int t = 0; t < 8; ++t) accT[t] = (f32x4){0.f, 0.f, 0.f, 0.f};
  }

  #pragma unroll
  for (int kc = 0; kc < 4; ++kc) {
    const short8 a = *(const short8*)&As[(wave * 16 + c) * 136 + kc * 32 + q * 8];
    if (t0 == 0) {
      #pragma unroll
      for (int t = 0; t < 8; ++t) {
        const short8 bb = *(const short8*)&Bf[((kc * 144 + t * 16 + c) * 4 + q) * 8];
        accT[t] = __builtin_amdgcn_mfma_f32_16x16x32_bf16(a, bb, accT[t], 0, 0, 0);
      }
    }
    const short8 b8 = *(const short8*)&Bf[((kc * 144 + 128 + c) * 4 + q) * 8];
    acc8 = __builtin_amdgcn_mfma_f32_16x16x32_bf16(a, b8, acc8, 0, 0, 0);
  }

  const int rbase = row0 + wave * 16 + q * 4;
  if (t0 == 0 && J.z[job]) {
    u16* zo = J.z[job];
    #pragma unroll
    for (int t = 0; t < 8; ++t)
      #pragma unroll
      for (int r = 0; r < 4; ++r) {
        const int row = rbase + r;
        if (row < N) zo[row * 128 + t * 16 + c] = f2bf(accT[t][r]);
      }
  }
  #pragma unroll
  for (int r = 0; r < 4; ++r) {
    const int row = rbase + r;
    if (row < N) {
      const float v = acc8[r];
      if (c < 8) { if (J.el[job]) J.el[job][row * 8 + c] = v; }
      else       { if (J.er[job]) J.er[job][row * 8 + (c - 8)] = v; }
    }
  }
}

// ---------------------------------------------------------------------------
// Batched CSR build over all 5 relations.
// ---------------------------------------------------------------------------
struct EJobs { const int* src[5]; const int* dst[5]; };
__device__ __forceinline__ int e_job(int e) {
  return (e >= 1000000) + (e >= 2000000) + (e >= 2500000) + (e >= 3500000);
}
__device__ __forceinline__ int e_base(int j) {
  const int base[5] = {0, 1000000, 2000000, 2500000, 3500000};
  return base[j];
}

__global__ __launch_bounds__(256) void k_count_all(EJobs J, int* __restrict__ counts) {
  const int e = blockIdx.x * 256 + threadIdx.x;
  if (e >= ETOT) return;
  const int j = e_job(e);
  const int d = J.dst[j][e - e_base(j)];
  atomicAdd(&counts[j * CSTRIDE + d], 1);
}

__global__ __launch_bounds__(1024) void k_scan_all(
    const int* __restrict__ counts, int* __restrict__ offsets)
{
  __shared__ int tsum[1024];
  const int rel = blockIdx.x;
  const int* cnt = counts + rel * CSTRIDE;
  int* off = offsets + rel * CSTRIDE;
  const int tid = threadIdx.x;
  const int n = 30000;
  const int chunk = 30;                       // 30*1024 >= 30000
  const int base = tid * chunk;
  int sum = 0;
  for (int i = 0; i < chunk; ++i) {
    const int idx = base + i;
    if (idx < n) sum += cnt[idx];
  }
  tsum[tid] = sum;
  __syncthreads();
  for (int o = 1; o < 1024; o <<= 1) {
    const int v = (tid >= o) ? tsum[tid - o] : 0;
    __syncthreads();
    tsum[tid] += v;
    __syncthreads();
  }
  int run = (tid == 0) ? 0 : tsum[tid - 1];
  for (int i = 0; i < chunk; ++i) {
    const int idx = base + i;
    if (idx < n) { off[idx] = run; run += cnt[idx]; }
  }
  if (tid == 1023) off[n] = tsum[1023];
}

__global__ __launch_bounds__(256) void k_fill_all(
    EJobs J, const int* __restrict__ offsets, int* __restrict__ counts,
    int* __restrict__ csr_src)
{
  const int e = blockIdx.x * 256 + threadIdx.x;
  if (e >= ETOT) return;
  const int j = e_job(e);
  const int le = e - e_base(j);
  const int d = J.dst[j][le];
  const int pos = atomicSub(&counts[j * CSTRIDE + d], 1) - 1;
  csr_src[e_base(j) + offsets[j * CSTRIDE + d] + pos] = J.src[j][le];
}

// ---------------------------------------------------------------------------
// Batched aggregation: 150000 waves (5 rel x 30000 dst). 4-edge unroll with
// dual accumulators to break the dependent-add chain.
// ---------------------------------------------------------------------------
struct AJobs { const int* csr[5]; const int* off[5]; const float* el[5];
               const float* er[5]; const u16* z[5]; const void* b[5];
               u16* feats[5]; int stride[5]; };
__global__ __launch_bounds__(256) void k_agg_all(AJobs J, const int* flagp) {
  const int gw = (blockIdx.x * 256 + threadIdx.x) >> 6;
  if (gw >= 150000) return;
  const int job = gw / 30000;
  const int d = gw - job * 30000;
  const int lane = threadIdx.x & 63;
  const int h = lane >> 3;
  const float* el = J.el[job];
  const u16* z = J.z[job];
  const int* csr = J.csr[job];
  const float erh = J.er[job][d * 8 + h];
  const int beg = J.off[job][d];
  const int end = J.off[job][d + 1];
  const int zoff = lane * 2;

  float a0 = 0.f, a1 = 0.f, b0 = 0.f, b1 = 0.f, dA = 0.f, dB = 0.f;
  int p = beg;
  for (; p + 4 <= end; p += 4) {
    const int s0 = csr[p];
    const int s1 = csr[p + 1];
    const int s2 = csr[p + 2];
    const int s3 = csr[p + 3];
    float e0 = el[s0 * 8 + h] + erh;
    float e1 = el[s1 * 8 + h] + erh;
    float e2 = el[s2 * 8 + h] + erh;
    float e3 = el[s3 * 8 + h] + erh;
    const unsigned int z0 = *(const unsigned int*)(z + s0 * 128 + zoff);
    const unsigned int z1 = *(const unsigned int*)(z + s1 * 128 + zoff);
    const unsigned int z2 = *(const unsigned int*)(z + s2 * 128 + zoff);
    const unsigned int z3 = *(const unsigned int*)(z + s3 * 128 + zoff);
    e0 = fminf((e0 >= 0.f) ? e0 : 0.2f * e0, 60.f);
    e1 = fminf((e1 >= 0.f) ? e1 : 0.2f * e1, 60.f);
    e2 = fminf((e2 >= 0.f) ? e2 : 0.2f * e2, 60.f);
    e3 = fminf((e3 >= 0.f) ? e3 : 0.2f * e3, 60.f);
    const float x0 = __expf(e0);
    const float x1 = __expf(e1);
    const float x2 = __expf(e2);
    const float x3 = __expf(e3);
    dA += x0 + x2;
    dB += x1 + x3;
    a0 = fmaf(x0, bf2f((u16)(z0 & 0xffffu)), a0);
    a1 = fmaf(x0, bf2f((u16)(z0 >> 16)), a1);
    b0 = fmaf(x1, bf2f((u16)(z1 & 0xffffu)), b0);
    b1 = fmaf(x1, bf2f((u16)(z1 >> 16)), b1);
    a0 = fmaf(x2, bf2f((u16)(z2 & 0xffffu)), a0);
    a1 = fmaf(x2, bf2f((u16)(z2 >> 16)), a1);
    b0 = fmaf(x3, bf2f((u16)(z3 & 0xffffu)), b0);
    b1 = fmaf(x3, bf2f((u16)(z3 >> 16)), b1);
  }
  for (; p < end; ++p) {
    const int s0 = csr[p];
    float e0 = el[s0 * 8 + h] + erh;
    e0 = fminf((e0 >= 0.f) ? e0 : 0.2f * e0, 60.f);
    const float x0 = __expf(e0);
    const unsigned int z0 = *(const unsigned int*)(z + s0 * 128 + zoff);
    dA += x0;
    a0 = fmaf(x0, bf2f((u16)(z0 & 0xffffu)), a0);
    a1 = fmaf(x0, bf2f((u16)(z0 >> 16)), a1);
  }
  const float inv = 1.f / fmaxf(dA + dB, 1e-9f);
  const int isbf = *flagp;
  const int j0 = lane * 2;
  const float v0 = (a0 + b0) * inv + ld_in(J.b[job], j0, isbf);
  const float v1 = (a1 + b1) * inv + ld_in(J.b[job], j0 + 1, isbf);
  const unsigned int packed = (unsigned int)f2bf(v0) | ((unsigned int)f2bf(v1) << 16);
  *(unsigned int*)(J.feats[job] + d * J.stride[job] + j0) = packed;
}

// ---------------------------------------------------------------------------
// Batched MFMA semantic score over 150000 contiguous feat rows.
// ---------------------------------------------------------------------------
__global__ __launch_bounds__(256) void k_sem_all(
    const u16* __restrict__ f, const u16* __restrict__ w1pack,
    const void* __restrict__ b1, const void* __restrict__ W2,
    const void* __restrict__ b2, float* __restrict__ s_out, int total,
    const int* __restrict__ flagp)
{
  __shared__ __align__(16) u16 Bf[18432];
  __shared__ __align__(16) u16 As[64 * 136];
  __shared__ float b1S[128], W2S[128];
  const int tid = threadIdx.x;
  const int isbf = *flagp;
  const int row0 = blockIdx.x * 64;

  for (int i = tid * 8; i < 18432; i += 2048)
    *(uint4*)&Bf[i] = *(const uint4*)&w1pack[i];
  if (tid < 128) { b1S[tid] = ld_in(b1, tid, isbf); W2S[tid] = ld_in(W2, tid, isbf); }
  {
    const uint4* xv = (const uint4*)f;
    for (int i = tid; i < 1024; i += 256) {
      const int r = i >> 4, c8 = i & 15;
      const int row = row0 + r;
      uint4 v = make_uint4(0, 0, 0, 0);
      if (row < total) v = xv[row * 16 + c8];
      *(uint4*)&As[r * 136 + c8 * 8] = v;
    }
  }
  __syncthreads();

  const int wave = tid >> 6;
  const int lane = tid & 63;
  const int q = lane >> 4;
  const int c = lane & 15;

  f32x4 acc[8];
  #pragma unroll
  for (int t = 0; t < 8; ++t) acc[t] = (f32x4){0.f, 0.f, 0.f, 0.f};

  #pragma unroll
  for (int kc = 0; kc < 4; ++kc) {
    const short8 a = *(const short8*)&As[(wave * 16 + c) * 136 + kc * 32 + q * 8];
    #pragma unroll
    for (int t = 0; t < 8; ++t) {
      const short8 bb = *(const short8*)&Bf[((kc * 144 + t * 16 + c) * 4 + q) * 8];
      acc[t] = __builtin_amdgcn_mfma_f32_16x16x32_bf16(a, bb, acc[t], 0, 0, 0);
    }
  }

  float part[4] = {0.f, 0.f, 0.f, 0.f};
  #pragma unroll
  for (int t = 0; t < 8; ++t) {
    const int n = t * 16 + c;
    const float b1v = b1S[n];
    const float w2v = W2S[n];
    #pragma unroll
    for (int r = 0; r < 4; ++r) {
      const float hv = acc[t][r] + b1v;
      const float e = __expf(2.f * hv);
      const float th = 1.f - 2.f / (e + 1.f);
      part[r] = fmaf(th, w2v, part[r]);
    }
  }
  #pragma unroll
  for (int r = 0; r < 4; ++r) {
    part[r] += __shfl_xor(part[r], 1);
    part[r] += __shfl_xor(part[r], 2);
    part[r] += __shfl_xor(part[r], 4);
    part[r] += __shfl_xor(part[r], 8);
  }
  if (c == 0) {
    const float b2v = ld_in(b2, 0, isbf);
    #pragma unroll
    for (int r = 0; r < 4; ++r) {
      const int row = row0 + wave * 16 + q * 4 + r;
      if (row < total) s_out[row] = part[r] + b2v;
    }
  }
}

// ---------------------------------------------------------------------------
// Batched combine: i<3.84M = drug (R=3), else prot (R=2). out[i] direct.
// ---------------------------------------------------------------------------
__global__ __launch_bounds__(256) void k_combine_all(
    const u16* __restrict__ feats, const float* __restrict__ s,
    void* __restrict__ out, const int* __restrict__ flagp)
{
  const int i = blockIdx.x * 256 + threadIdx.x;
  if (i >= 7680000) return;
  const int isbf = *flagp;
  const bool drug = (i < 3840000);
  const int li = drug ? i : i - 3840000;
  const int n = li >> 7;
  const int j = li & 127;
  const int R = drug ? 3 : 2;
  const float* sr = s + (drug ? n * 3 : 90000 + n * 2);
  const u16* fb = feats + (drug ? n * 384 : 11520000 + n * 256);
  const float s0v = sr[0];
  const float s1v = sr[1];
  const float s2v = drug ? sr[2] : -3.4e38f;
  const float m = fmaxf(fmaxf(s0v, s1v), s2v);
  const float w0 = __expf(s0v - m);
  const float w1 = __expf(s1v - m);
  const float w2 = drug ? __expf(s2v - m) : 0.f;
  const float inv = 1.f / (w0 + w1 + w2);
  float acc = w0 * bf2f(fb[j]) + w1 * bf2f(fb[128 + j]);
  if (R == 3) acc += w2 * bf2f(fb[256 + j]);
  const float v = acc * inv;
  if (isbf) ((u16*)out)[i] = f2bf(v);
  else      ((float*)out)[i] = v;
}

extern "C" void kernel_launch(void* const* d_in, const int* in_sizes, int n_in,
                              void* d_out, int out_size, void* d_ws, size_t ws_size,
                              hipStream_t stream)
{
  (void)in_sizes; (void)n_in; (void)out_size; (void)ws_size;

  const void* h_drug = d_in[0];
  const void* h_prot = d_in[1];
  const void* h_se   = d_in[2];
  const void* W_dd = d_in[3];  const void* al_dd = d_in[4];
  const void* ar_dd = d_in[5]; const void* b_dd  = d_in[6];
  const void* W_dp = d_in[7];  const void* al_dp = d_in[8];
  const void* ar_dp = d_in[9]; const void* b_dp  = d_in[10];
  const void* W_pd = d_in[11]; const void* al_pd = d_in[12];
  const void* ar_pd = d_in[13];const void* b_pd  = d_in[14];
  const void* W_pp = d_in[15]; const void* al_pp = d_in[16];
  const void* ar_pp = d_in[17];const void* b_pp  = d_in[18];
  const void* W_sd = d_in[19]; const void* al_sd = d_in[20];
  const void* ar_sd = d_in[21];const void* b_sd  = d_in[22];
  const void* W1 = d_in[23];   const void* b1 = d_in[24];
  const void* W2 = d_in[25];   const void* b2 = d_in[26];
  const int* src_dd = (const int*)d_in[27];
  const int* dst_dd = (const int*)d_in[28];
  const int* src_dp = (const int*)d_in[29];
  const int* dst_dp = (const int*)d_in[30];
  const int* src_pd = (const int*)d_in[31];
  const int* dst_pd = (const int*)d_in[32];
  const int* src_pp = (const int*)d_in[33];
  const int* dst_pp = (const int*)d_in[34];
  const int* src_sd = (const int*)d_in[35];
  const int* dst_sd = (const int*)d_in[36];

  // ---- workspace layout (~101.4 MB; R1 demonstrated >=124 MB usable) ----
  char* w = (char*)d_ws;
  float* el5   = (float*)(w);                    // 5 x 240,000 f32 = 4,800,000 B
  float* er5   = (float*)(w + 4800000);          // 4,800,000 B
  u16* z_dd    = (u16*)(w + 9600000);            // 7,680,000 B
  u16* z_pd    = (u16*)(w + 17280000);           // 7,680,000 B
  u16* z_sd    = (u16*)(w + 24960000);           // 2,560,000 B
  u16* z_dp    = (u16*)(w + 27520000);           // 7,680,000 B
  u16* z_pp    = (u16*)(w + 35200000);           // 7,680,000 B
  int* counts  = (int*)(w + 42880000);           // 600,320 B
  int* offsets = (int*)(w + 43480320);           // 600,320 B
  int* csr     = (int*)(w + 44080640);           // 18,000,000 B
  float* s     = (float*)(w + 62080640);         // 600,000 B
  u16* feats   = (u16*)(w + 62680640);           // 38,400,000 B
  int* flag    = (int*)(w + 101080640);          // 16 B
  float* ww    = (float*)(w + 101080656);        // 40,960 B (wal/war x5)
  u16* packs   = (u16*)(w + 101121616);          // 6 x 36,864 B

  float *wal[5], *war[5];
  for (int r = 0; r < 5; ++r) { wal[r] = ww + r * 2048; war[r] = ww + r * 2048 + 1024; }
  u16* pk[6];
  for (int r = 0; r < 6; ++r) pk[r] = packs + r * 18432;
  float* el_r[5]; float* er_r[5];
  for (int r = 0; r < 5; ++r) { el_r[r] = el5 + r * 240000; er_r[r] = er5 + r * 240000; }
  u16* feats_d = feats;               // drug: 30000 x 384
  u16* feats_p = feats + 11520000;    // prot: 30000 x 256

  const dim3 blk(256);

  k_detect<<<dim3(1), dim3(64), 0, stream>>>(h_drug, flag);

  // rel order: 0=dd 1=pd 2=sd 3=dp 4=pp
  PJobs pj;
  pj.W[0]=W_dd; pj.al[0]=al_dd; pj.ar[0]=ar_dd;
  pj.W[1]=W_pd; pj.al[1]=al_pd; pj.ar[1]=ar_pd;
  pj.W[2]=W_sd; pj.al[2]=al_sd; pj.ar[2]=ar_sd;
  pj.W[3]=W_dp; pj.al[3]=al_dp; pj.ar[3]=ar_dp;
  pj.W[4]=W_pp; pj.al[4]=al_pp; pj.ar[4]=ar_pp;
  for (int r = 0; r < 5; ++r) { pj.wal[r] = wal[r]; pj.war[r] = war[r]; }
  k_prep_all<<<dim3(5), dim3(128), 0, stream>>>(pj, flag);

  KPack kp;
  kp.W[0]=W_dd; kp.W[1]=W_pd; kp.W[2]=W_sd; kp.W[3]=W_dp; kp.W[4]=W_pp; kp.W[5]=W1;
  for (int r = 0; r < 5; ++r) { kp.wal[r] = wal[r]; kp.war[r] = war[r]; }
  kp.wal[5]=nullptr; kp.war[5]=nullptr;
  for (int r = 0; r < 6; ++r) kp.out[r] = pk[r];
  k_pack_all<<<dim3(54), blk, 0, stream>>>(kp, flag);

  // ---- CSR build (all relations) ----
  (void)hipMemsetAsync(counts, 0, 600320, stream);
  EJobs ej;
  ej.src[0]=src_dd; ej.dst[0]=dst_dd;
  ej.src[1]=src_pd; ej.dst[1]=dst_pd;
  ej.src[2]=src_sd; ej.dst[2]=dst_sd;
  ej.src[3]=src_dp; ej.dst[3]=dst_dp;
  ej.src[4]=src_pp; ej.dst[4]=dst_pp;
  k_count_all<<<dim3((ETOT + 255) / 256), blk, 0, stream>>>(ej, counts);
  k_scan_all<<<dim3(5), dim3(1024), 0, stream>>>(counts, offsets);
  k_fill_all<<<dim3((ETOT + 255) / 256), blk, 0, stream>>>(ej, offsets, counts, csr);

  // ---- transforms (8 jobs, one launch) ----
  XJobs xj;
  auto setx = [&](int i, const void* x, const u16* bp, u16* z, float* el,
                  float* er, int N, int t0) {
    xj.x[i]=x; xj.bp[i]=bp; xj.z[i]=z; xj.el[i]=el; xj.er[i]=er; xj.N[i]=N; xj.t0[i]=t0;
  };
  setx(0, h_drug, pk[0], z_dd, el_r[0], er_r[0], ND, 0);   // dd
  setx(1, h_prot, pk[1], z_pd, el_r[1], nullptr, NP, 0);   // pd src
  setx(2, h_drug, pk[1], nullptr, nullptr, er_r[1], ND, 8);// pd dst
  setx(3, h_se,   pk[2], z_sd, el_r[2], nullptr, NS, 0);   // sd src
  setx(4, h_drug, pk[2], nullptr, nullptr, er_r[2], ND, 8);// sd dst
  setx(5, h_drug, pk[3], z_dp, el_r[3], nullptr, ND, 0);   // dp src
  setx(6, h_prot, pk[3], nullptr, nullptr, er_r[3], NP, 8);// dp dst
  setx(7, h_prot, pk[4], z_pp, el_r[4], er_r[4], NP, 0);   // pp
  {
    int acc = 0;
    for (int i = 0; i < 8; ++i) { xj.blk0[i] = acc; acc += (xj.N[i] + 63) / 64; }
    xj.blk0[8] = acc;
    k_xform_all<<<dim3(acc), blk, 0, stream>>>(xj, flag);
  }

  // ---- aggregation (one launch, 150000 waves) ----
  AJobs aj;
  const int ebase[5] = {0, 1000000, 2000000, 2500000, 3500000};
  const void* bias[5] = {b_dd, b_pd, b_sd, b_dp, b_pp};
  u16* fb[5] = {feats_d, feats_d + 128, feats_d + 256, feats_p, feats_p + 128};
  const int fstride[5] = {384, 384, 384, 256, 256};
  const u16* zz[5] = {z_dd, z_pd, z_sd, z_dp, z_pp};
  for (int r = 0; r < 5; ++r) {
    aj.csr[r] = csr + ebase[r];
    aj.off[r] = offsets + r * CSTRIDE;
    aj.el[r] = el_r[r];
    aj.er[r] = er_r[r];
    aj.z[r] = zz[r];
    aj.b[r] = bias[r];
    aj.feats[r] = fb[r];
    aj.stride[r] = fstride[r];
  }
  k_agg_all<<<dim3(150000 / 4), blk, 0, stream>>>(aj, flag);

  // ---- semantic attention + combine ----
  k_sem_all<<<dim3((150000 + 63) / 64), blk, 0, stream>>>(feats, pk[5], b1, W2, b2, s, 150000, flag);
  k_combine_all<<<dim3((7680000 + 255) / 256), blk, 0, stream>>>(feats, s, d_out, flag);
}

// Round 7
// 608.095 us; speedup vs baseline: 27.8904x; 1.5594x over previous
//
#include <hip/hip_runtime.h>
#include <hip/hip_bf16.h>

typedef unsigned short u16;
typedef __attribute__((ext_vector_type(8))) short short8;   // 8 bf16 (4 VGPRs)
typedef __attribute__((ext_vector_type(4))) float f32x4;

#define ND 30000
#define NP 30000
#define NS 10000
#define CSTRIDE 30016          // offsets per-relation stride (ints)
#define ETOT 4500000
#define CHUNK 4608             // edges per chunk (18 per thread)
#define NC 977                 // ceil(ETOT/CHUNK)
#define NBR 118                // buckets per relation (256 dsts each)
#define NB 590                 // total buckets

__device__ __forceinline__ float bf2f(u16 u) {
  union { unsigned int i; float f; } c; c.i = ((unsigned int)u) << 16; return c.f;
}
__device__ __forceinline__ u16 f2bf(float f) {
  union { float f; unsigned int i; } c; c.f = f;
  unsigned int u = c.i;
  unsigned int r = (u + 0x7fffu + ((u >> 16) & 1u)) >> 16;
  return (u16)r;
}

__global__ void k_detect(const void* x, int* flag) {
  if (threadIdx.x == 0 && blockIdx.x == 0) {
    const u16* p = (const u16*)x;
    int sane = 0;
    for (int i = 0; i < 256; ++i) {
      const u16 v = p[2 * i];
      const int e = (v >> 7) & 0xff;
      sane += (e >= 100 && e <= 140) ? 1 : 0;
    }
    *flag = (sane >= 200) ? 1 : 0;   // 1 = bf16, 0 = fp32
  }
}

__device__ __forceinline__ float ld_in(const void* p, int i, int isbf) {
  return isbf ? bf2f(((const u16*)p)[i]) : ((const float*)p)[i];
}

// ---------------------------------------------------------------------------
// Wal[h][k] = sum_d W[k][h*16+d]*al[h*16+d] (and War). Block b = relation b.
// ---------------------------------------------------------------------------
struct PJobs { const void* W[5]; const void* al[5]; const void* ar[5];
               float* wal[5]; float* war[5]; };
__global__ __launch_bounds__(128) void k_prep_all(PJobs J, const int* flagp) {
  const int b = blockIdx.x;
  const int k = threadIdx.x;
  const int isbf = *flagp;
  for (int h = 0; h < 8; ++h) {
    float sa = 0.f, sr = 0.f;
    for (int d = 0; d < 16; ++d) {
      const float wv = ld_in(J.W[b], k * 128 + h * 16 + d, isbf);
      sa = fmaf(wv, ld_in(J.al[b], h * 16 + d, isbf), sa);
      sr = fmaf(wv, ld_in(J.ar[b], h * 16 + d, isbf), sr);
    }
    J.wal[b][h * 128 + k] = sa;
    J.war[b][h * 128 + k] = sr;
  }
}

// ---------------------------------------------------------------------------
// Pre-pack B into MFMA fragment order (proven R6).
// ---------------------------------------------------------------------------
struct KPack { const void* W[6]; const float* wal[6]; const float* war[6];
               u16* out[6]; };
__global__ __launch_bounds__(256) void k_pack_all(KPack J, const int* flagp) {
  const int job = blockIdx.x / 9;
  const int i0 = (blockIdx.x % 9) * 2048 + threadIdx.x * 8;
  const int isbf = *flagp;
  const int kc = i0 / 4608;
  const int rem = i0 - kc * 4608;
  const int n = rem >> 5;
  const int q = (rem >> 3) & 3;
  u16 vals[8];
  #pragma unroll
  for (int j = 0; j < 8; ++j) {
    const int k = kc * 32 + q * 8 + j;
    float v;
    if (job == 5)      v = (n < 128) ? ld_in(J.W[5], k * 128 + n, isbf) : 0.f;
    else if (n < 128)  v = ld_in(J.W[job], k * 128 + n, isbf);
    else if (n < 136)  v = J.wal[job][(n - 128) * 128 + k];
    else               v = J.war[job][(n - 136) * 128 + k];
    vals[j] = f2bf(v);
  }
  *(uint4*)&J.out[job][i0] = *(uint4*)vals;
}

// ---------------------------------------------------------------------------
// Batched MFMA transform (proven R6).
// ---------------------------------------------------------------------------
struct XJobs {
  const void* x[8]; const u16* bp[8]; u16* z[8]; float* el[8]; float* er[8];
  int N[8]; int t0[8]; int blk0[9];
};
__global__ __launch_bounds__(256) void k_xform_all(XJobs J, const int* flagp) {
  __shared__ __align__(16) u16 Bf[18432];
  __shared__ __align__(16) u16 As[64 * 136];
  const int tid = threadIdx.x;
  const int isbf = *flagp;

  int job = 0, b = blockIdx.x;
  while (b >= J.blk0[job + 1]) ++job;
  const int row0 = (b - J.blk0[job]) * 64;
  const int N = J.N[job];
  const int t0 = J.t0[job];
  const u16* bp = J.bp[job];
  const void* x = J.x[job];

  if (t0 == 0) {
    for (int i = tid * 8; i < 18432; i += 2048)
      *(uint4*)&Bf[i] = *(const uint4*)&bp[i];
  } else {
    const int i = tid * 8;
    const int kc = i >> 9;
    const int off = (kc * 144 + 128) * 32 + (i & 511);
    *(uint4*)&Bf[off] = *(const uint4*)&bp[off];
  }

  if (isbf) {
    const uint4* xv = (const uint4*)x;
    for (int i = tid; i < 1024; i += 256) {
      const int r = i >> 4, c8 = i & 15;
      const int row = row0 + r;
      uint4 v = make_uint4(0, 0, 0, 0);
      if (row < N) v = xv[row * 16 + c8];
      *(uint4*)&As[r * 136 + c8 * 8] = v;
    }
  } else {
    const float4* xf = (const float4*)x;
    for (int i = tid; i < 2048; i += 256) {
      const int r = i >> 5, c4 = i & 31;
      const int row = row0 + r;
      unsigned long long pk = 0ull;
      if (row < N) {
        const float4 v = xf[row * 32 + c4];
        pk = (unsigned long long)f2bf(v.x) | ((unsigned long long)f2bf(v.y) << 16)
           | ((unsigned long long)f2bf(v.z) << 32) | ((unsigned long long)f2bf(v.w) << 48);
      }
      *(unsigned long long*)&As[r * 136 + c4 * 4] = pk;
    }
  }
  __syncthreads();

  const int wave = tid >> 6;
  const int lane = tid & 63;
  const int q = lane >> 4;
  const int c = lane & 15;

  f32x4 accT[8];
  f32x4 acc8 = (f32x4){0.f, 0.f, 0.f, 0.f};
  if (t0 == 0) {
    #pragma unroll
    for (int t = 0; t < 8; ++t) accT[t] = (f32x4){0.f, 0.f, 0.f, 0.f};
  }

  #pragma unroll
  for (int kc = 0; kc < 4; ++kc) {
    const short8 a = *(const short8*)&As[(wave * 16 + c) * 136 + kc * 32 + q * 8];
    if (t0 == 0) {
      #pragma unroll
      for (int t = 0; t < 8; ++t) {
        const short8 bb = *(const short8*)&Bf[((kc * 144 + t * 16 + c) * 4 + q) * 8];
        accT[t] = __builtin_amdgcn_mfma_f32_16x16x32_bf16(a, bb, accT[t], 0, 0, 0);
      }
    }
    const short8 b8 = *(const short8*)&Bf[((kc * 144 + 128 + c) * 4 + q) * 8];
    acc8 = __builtin_amdgcn_mfma_f32_16x16x32_bf16(a, b8, acc8, 0, 0, 0);
  }

  const int rbase = row0 + wave * 16 + q * 4;
  if (t0 == 0 && J.z[job]) {
    u16* zo = J.z[job];
    #pragma unroll
    for (int t = 0; t < 8; ++t)
      #pragma unroll
      for (int r = 0; r < 4; ++r) {
        const int row = rbase + r;
        if (row < N) zo[row * 128 + t * 16 + c] = f2bf(accT[t][r]);
      }
  }
  #pragma unroll
  for (int r = 0; r < 4; ++r) {
    const int row = rbase + r;
    if (row < N) {
      const float v = acc8[r];
      if (c < 8) { if (J.el[job]) J.el[job][row * 8 + c] = v; }
      else       { if (J.er[job]) J.er[job][row * 8 + (c - 8)] = v; }
    }
  }
}

// ---------------------------------------------------------------------------
// Atomic-free CSR build: hist -> bucketscan -> base -> bin -> fill2.
// Bucket = 256 consecutive dsts; all cursors live in LDS.
// ---------------------------------------------------------------------------
struct EJobs { const int* src[5]; const int* dst[5]; };
__device__ __forceinline__ int e_job(int e) {
  return (e >= 1000000) + (e >= 2000000) + (e >= 2500000) + (e >= 3500000);
}
__device__ __forceinline__ int e_base(int j) {
  const int base[6] = {0, 1000000, 2000000, 2500000, 3500000, 4500000};
  return base[j];
}

__global__ __launch_bounds__(256) void k_hist(EJobs J, int* __restrict__ ghist) {
  __shared__ int h[NB];
  const int c = blockIdx.x, tid = threadIdx.x;
  for (int i = tid; i < NB; i += 256) h[i] = 0;
  __syncthreads();
  const int e0 = c * CHUNK;
  #pragma unroll
  for (int t = 0; t < 18; ++t) {
    const int e = e0 + t * 256 + tid;
    if (e < ETOT) {
      const int j = e_job(e);
      const int d = J.dst[j][e - e_base(j)];
      atomicAdd(&h[j * NBR + (d >> 8)], 1);
    }
  }
  __syncthreads();
  for (int i = tid; i < NB; i += 256) ghist[c * NB + i] = h[i];
}

__global__ __launch_bounds__(256) void k_bucketscan(
    const int* __restrict__ ghist, int* __restrict__ gcur, int* __restrict__ totals)
{
  __shared__ int ts[256];
  const int b = blockIdx.x, tid = threadIdx.x;
  int v[4]; int sum = 0;
  #pragma unroll
  for (int i = 0; i < 4; ++i) {
    const int c = tid * 4 + i;
    v[i] = (c < NC) ? ghist[c * NB + b] : 0;
    sum += v[i];
  }
  ts[tid] = sum;
  __syncthreads();
  for (int o = 1; o < 256; o <<= 1) {
    const int x = (tid >= o) ? ts[tid - o] : 0;
    __syncthreads();
    ts[tid] += x;
    __syncthreads();
  }
  int run = (tid == 0) ? 0 : ts[tid - 1];
  #pragma unroll
  for (int i = 0; i < 4; ++i) {
    const int c = tid * 4 + i;
    if (c < NC) gcur[b * NC + c] = run;
    run += v[i];
  }
  if (tid == 255) totals[b] = ts[255];
}

__global__ __launch_bounds__(1024) void k_base(
    const int* __restrict__ totals, int* __restrict__ base)
{
  __shared__ int ts[1024];
  const int tid = threadIdx.x;
  ts[tid] = (tid < NB) ? totals[tid] : 0;
  __syncthreads();
  for (int o = 1; o < 1024; o <<= 1) {
    const int x = (tid >= o) ? ts[tid - o] : 0;
    __syncthreads();
    ts[tid] += x;
    __syncthreads();
  }
  if (tid < NB) base[tid] = (tid == 0) ? 0 : ts[tid - 1];
  if (tid == 0) base[NB] = ETOT;
}

__global__ __launch_bounds__(256) void k_bin(
    EJobs J, const int* __restrict__ gcur, const int* __restrict__ base,
    unsigned int* __restrict__ bin)
{
  __shared__ int cur[NB];
  const int c = blockIdx.x, tid = threadIdx.x;
  for (int i = tid; i < NB; i += 256) cur[i] = base[i] + gcur[i * NC + c];
  __syncthreads();
  const int e0 = c * CHUNK;
  #pragma unroll
  for (int t = 0; t < 18; ++t) {
    const int e = e0 + t * 256 + tid;
    if (e < ETOT) {
      const int j = e_job(e);
      const int le = e - e_base(j);
      const int d = J.dst[j][le];
      const int s = J.src[j][le];
      const int p = atomicAdd(&cur[j * NBR + (d >> 8)], 1);
      bin[p] = ((unsigned int)(d & 255) << 16) | (unsigned int)s;
    }
  }
}

__global__ __launch_bounds__(256) void k_fill2(
    const unsigned int* __restrict__ bin, const int* __restrict__ base,
    u16* __restrict__ csr, int* __restrict__ offsets)
{
  __shared__ int cnt[256], curs[256];
  const int b = blockIdx.x, tid = threadIdx.x;
  const int rel = b / NBR;
  const int bloc = b - rel * NBR;
  const int d0 = bloc << 8;
  const int gbeg = base[b];
  const int n = base[b + 1] - gbeg;
  cnt[tid] = 0;
  __syncthreads();
  for (int i = tid; i < n; i += 256)
    atomicAdd(&cnt[bin[gbeg + i] >> 16], 1);
  __syncthreads();
  const int orig = cnt[tid];
  for (int o = 1; o < 256; o <<= 1) {
    const int x = (tid >= o) ? cnt[tid - o] : 0;
    __syncthreads();
    cnt[tid] += x;
    __syncthreads();
  }
  const int ex = cnt[tid] - orig;
  curs[tid] = ex;
  const int ebr = e_base(rel);
  const int d = d0 + tid;
  if (d < 30000) offsets[rel * CSTRIDE + d] = (gbeg - ebr) + ex;
  if (bloc == NBR - 1 && tid == 0)
    offsets[rel * CSTRIDE + 30000] = e_base(rel + 1) - ebr;
  __syncthreads();
  for (int i = tid; i < n; i += 256) {
    const unsigned int v = bin[gbeg + i];
    const int p = atomicAdd(&curs[v >> 16], 1);
    csr[gbeg + p] = (u16)(v & 0xffffu);
  }
}

// ---------------------------------------------------------------------------
// Batched aggregation (proven R6; csr now u16).
// ---------------------------------------------------------------------------
struct AJobs { const u16* csr[5]; const int* off[5]; const float* el[5];
               const float* er[5]; const u16* z[5]; const void* b[5];
               u16* feats[5]; int stride[5]; };
__global__ __launch_bounds__(256) void k_agg_all(AJobs J, const int* flagp) {
  const int gw = (blockIdx.x * 256 + threadIdx.x) >> 6;
  if (gw >= 150000) return;
  const int job = gw / 30000;
  const int d = gw - job * 30000;
  const int lane = threadIdx.x & 63;
  const int h = lane >> 3;
  const float* el = J.el[job];
  const u16* z = J.z[job];
  const u16* csr = J.csr[job];
  const float erh = J.er[job][d * 8 + h];
  const int beg = J.off[job][d];
  const int end = J.off[job][d + 1];
  const int zoff = lane * 2;

  float a0 = 0.f, a1 = 0.f, b0 = 0.f, b1 = 0.f, dA = 0.f, dB = 0.f;
  int p = beg;
  for (; p + 4 <= end; p += 4) {
    const int s0 = csr[p];
    const int s1 = csr[p + 1];
    const int s2 = csr[p + 2];
    const int s3 = csr[p + 3];
    float e0 = el[s0 * 8 + h] + erh;
    float e1 = el[s1 * 8 + h] + erh;
    float e2 = el[s2 * 8 + h] + erh;
    float e3 = el[s3 * 8 + h] + erh;
    const unsigned int z0 = *(const unsigned int*)(z + s0 * 128 + zoff);
    const unsigned int z1 = *(const unsigned int*)(z + s1 * 128 + zoff);
    const unsigned int z2 = *(const unsigned int*)(z + s2 * 128 + zoff);
    const unsigned int z3 = *(const unsigned int*)(z + s3 * 128 + zoff);
    e0 = fminf((e0 >= 0.f) ? e0 : 0.2f * e0, 60.f);
    e1 = fminf((e1 >= 0.f) ? e1 : 0.2f * e1, 60.f);
    e2 = fminf((e2 >= 0.f) ? e2 : 0.2f * e2, 60.f);
    e3 = fminf((e3 >= 0.f) ? e3 : 0.2f * e3, 60.f);
    const float x0 = __expf(e0);
    const float x1 = __expf(e1);
    const float x2 = __expf(e2);
    const float x3 = __expf(e3);
    dA += x0 + x2;
    dB += x1 + x3;
    a0 = fmaf(x0, bf2f((u16)(z0 & 0xffffu)), a0);
    a1 = fmaf(x0, bf2f((u16)(z0 >> 16)), a1);
    b0 = fmaf(x1, bf2f((u16)(z1 & 0xffffu)), b0);
    b1 = fmaf(x1, bf2f((u16)(z1 >> 16)), b1);
    a0 = fmaf(x2, bf2f((u16)(z2 & 0xffffu)), a0);
    a1 = fmaf(x2, bf2f((u16)(z2 >> 16)), a1);
    b0 = fmaf(x3, bf2f((u16)(z3 & 0xffffu)), b0);
    b1 = fmaf(x3, bf2f((u16)(z3 >> 16)), b1);
  }
  for (; p < end; ++p) {
    const int s0 = csr[p];
    float e0 = el[s0 * 8 + h] + erh;
    e0 = fminf((e0 >= 0.f) ? e0 : 0.2f * e0, 60.f);
    const float x0 = __expf(e0);
    const unsigned int z0 = *(const unsigned int*)(z + s0 * 128 + zoff);
    dA += x0;
    a0 = fmaf(x0, bf2f((u16)(z0 & 0xffffu)), a0);
    a1 = fmaf(x0, bf2f((u16)(z0 >> 16)), a1);
  }
  const float inv = 1.f / fmaxf(dA + dB, 1e-9f);
  const int isbf = *flagp;
  const int j0 = lane * 2;
  const float v0 = (a0 + b0) * inv + ld_in(J.b[job], j0, isbf);
  const float v1 = (a1 + b1) * inv + ld_in(J.b[job], j0 + 1, isbf);
  const unsigned int packed = (unsigned int)f2bf(v0) | ((unsigned int)f2bf(v1) << 16);
  *(unsigned int*)(J.feats[job] + d * J.stride[job] + j0) = packed;
}

// ---------------------------------------------------------------------------
// Batched MFMA semantic score (proven R6).
// ---------------------------------------------------------------------------
__global__ __launch_bounds__(256) void k_sem_all(
    const u16* __restrict__ f, const u16* __restrict__ w1pack,
    const void* __restrict__ b1, const void* __restrict__ W2,
    const void* __restrict__ b2, float* __restrict__ s_out, int total,
    const int* __restrict__ flagp)
{
  __shared__ __align__(16) u16 Bf[18432];
  __shared__ __align__(16) u16 As[64 * 136];
  __shared__ float b1S[128], W2S[128];
  const int tid = threadIdx.x;
  const int isbf = *flagp;
  const int row0 = blockIdx.x * 64;

  for (int i = tid * 8; i < 18432; i += 2048)
    *(uint4*)&Bf[i] = *(const uint4*)&w1pack[i];
  if (tid < 128) { b1S[tid] = ld_in(b1, tid, isbf); W2S[tid] = ld_in(W2, tid, isbf); }
  {
    const uint4* xv = (const uint4*)f;
    for (int i = tid; i < 1024; i += 256) {
      const int r = i >> 4, c8 = i & 15;
      const int row = row0 + r;
      uint4 v = make_uint4(0, 0, 0, 0);
      if (row < total) v = xv[row * 16 + c8];
      *(uint4*)&As[r * 136 + c8 * 8] = v;
    }
  }
  __syncthreads();

  const int wave = tid >> 6;
  const int lane = tid & 63;
  const int q = lane >> 4;
  const int c = lane & 15;

  f32x4 acc[8];
  #pragma unroll
  for (int t = 0; t < 8; ++t) acc[t] = (f32x4){0.f, 0.f, 0.f, 0.f};

  #pragma unroll
  for (int kc = 0; kc < 4; ++kc) {
    const short8 a = *(const short8*)&As[(wave * 16 + c) * 136 + kc * 32 + q * 8];
    #pragma unroll
    for (int t = 0; t < 8; ++t) {
      const short8 bb = *(const short8*)&Bf[((kc * 144 + t * 16 + c) * 4 + q) * 8];
      acc[t] = __builtin_amdgcn_mfma_f32_16x16x32_bf16(a, bb, acc[t], 0, 0, 0);
    }
  }

  float part[4] = {0.f, 0.f, 0.f, 0.f};
  #pragma unroll
  for (int t = 0; t < 8; ++t) {
    const int n = t * 16 + c;
    const float b1v = b1S[n];
    const float w2v = W2S[n];
    #pragma unroll
    for (int r = 0; r < 4; ++r) {
      const float hv = acc[t][r] + b1v;
      const float e = __expf(2.f * hv);
      const float th = 1.f - 2.f / (e + 1.f);
      part[r] = fmaf(th, w2v, part[r]);
    }
  }
  #pragma unroll
  for (int r = 0; r < 4; ++r) {
    part[r] += __shfl_xor(part[r], 1);
    part[r] += __shfl_xor(part[r], 2);
    part[r] += __shfl_xor(part[r], 4);
    part[r] += __shfl_xor(part[r], 8);
  }
  if (c == 0) {
    const float b2v = ld_in(b2, 0, isbf);
    #pragma unroll
    for (int r = 0; r < 4; ++r) {
      const int row = row0 + wave * 16 + q * 4 + r;
      if (row < total) s_out[row] = part[r] + b2v;
    }
  }
}

// ---------------------------------------------------------------------------
// Batched combine (proven R6).
// ---------------------------------------------------------------------------
__global__ __launch_bounds__(256) void k_combine_all(
    const u16* __restrict__ feats, const float* __restrict__ s,
    void* __restrict__ out, const int* __restrict__ flagp)
{
  const int i = blockIdx.x * 256 + threadIdx.x;
  if (i >= 7680000) return;
  const int isbf = *flagp;
  const bool drug = (i < 3840000);
  const int li = drug ? i : i - 3840000;
  const int n = li >> 7;
  const int j = li & 127;
  const float* sr = s + (drug ? n * 3 : 90000 + n * 2);
  const u16* fb = feats + (drug ? n * 384 : 11520000 + n * 256);
  const float s0v = sr[0];
  const float s1v = sr[1];
  const float s2v = drug ? sr[2] : -3.4e38f;
  const float m = fmaxf(fmaxf(s0v, s1v), s2v);
  const float w0 = __expf(s0v - m);
  const float w1 = __expf(s1v - m);
  const float w2 = drug ? __expf(s2v - m) : 0.f;
  const float inv = 1.f / (w0 + w1 + w2);
  float acc = w0 * bf2f(fb[j]) + w1 * bf2f(fb[128 + j]);
  if (drug) acc += w2 * bf2f(fb[256 + j]);
  const float v = acc * inv;
  if (isbf) ((u16*)out)[i] = f2bf(v);
  else      ((float*)out)[i] = v;
}

extern "C" void kernel_launch(void* const* d_in, const int* in_sizes, int n_in,
                              void* d_out, int out_size, void* d_ws, size_t ws_size,
                              hipStream_t stream)
{
  (void)in_sizes; (void)n_in; (void)out_size; (void)ws_size;

  const void* h_drug = d_in[0];
  const void* h_prot = d_in[1];
  const void* h_se   = d_in[2];
  const void* W_dd = d_in[3];  const void* al_dd = d_in[4];
  const void* ar_dd = d_in[5]; const void* b_dd  = d_in[6];
  const void* W_dp = d_in[7];  const void* al_dp = d_in[8];
  const void* ar_dp = d_in[9]; const void* b_dp  = d_in[10];
  const void* W_pd = d_in[11]; const void* al_pd = d_in[12];
  const void* ar_pd = d_in[13];const void* b_pd  = d_in[14];
  const void* W_pp = d_in[15]; const void* al_pp = d_in[16];
  const void* ar_pp = d_in[17];const void* b_pp  = d_in[18];
  const void* W_sd = d_in[19]; const void* al_sd = d_in[20];
  const void* ar_sd = d_in[21];const void* b_sd  = d_in[22];
  const void* W1 = d_in[23];   const void* b1 = d_in[24];
  const void* W2 = d_in[25];   const void* b2 = d_in[26];
  const int* src_dd = (const int*)d_in[27];
  const int* dst_dd = (const int*)d_in[28];
  const int* src_dp = (const int*)d_in[29];
  const int* dst_dp = (const int*)d_in[30];
  const int* src_pd = (const int*)d_in[31];
  const int* dst_pd = (const int*)d_in[32];
  const int* src_pp = (const int*)d_in[33];
  const int* dst_pp = (const int*)d_in[34];
  const int* src_sd = (const int*)d_in[35];
  const int* dst_sd = (const int*)d_in[36];

  // ---- workspace layout (~96.4 MB <= 101.4 MB proven in R6) ----
  char* w = (char*)d_ws;
  float* el5   = (float*)(w);                    // 4,800,000
  float* er5   = (float*)(w + 4800000);          // 4,800,000
  u16* z_dd    = (u16*)(w + 9600000);            // 7,680,000
  u16* z_pd    = (u16*)(w + 17280000);           // 7,680,000
  u16* z_sd    = (u16*)(w + 24960000);           // 2,560,000
  u16* z_dp    = (u16*)(w + 27520000);           // 7,680,000
  u16* z_pp    = (u16*)(w + 35200000);           // 7,680,000
  int* offsets = (int*)(w + 42880000);           // 600,320
  u16* csr     = (u16*)(w + 43480320);           // 9,000,000
  int* ghist   = (int*)(w + 52480320);           // 2,305,720
  int* gcur    = (int*)(w + 54786048);           // 2,305,720
  int* basep   = (int*)(w + 57091776);           // 2,368
  float* s     = (float*)(w + 57094144);         // 600,000
  u16* feats   = (u16*)(w + 57694144);           // 38,400,000 (ends 96,094,144)
  unsigned int* bin = (unsigned int*)(w + 57694144); // aliases feats (dead before agg)
  int* flag    = (int*)(w + 96094144);           // 16
  float* ww    = (float*)(w + 96094160);         // 40,960
  u16* packs   = (u16*)(w + 96135120);           // 221,184 -> end 96,356,304

  float *wal[5], *war[5];
  for (int r = 0; r < 5; ++r) { wal[r] = ww + r * 2048; war[r] = ww + r * 2048 + 1024; }
  u16* pk[6];
  for (int r = 0; r < 6; ++r) pk[r] = packs + r * 18432;
  float* el_r[5]; float* er_r[5];
  for (int r = 0; r < 5; ++r) { el_r[r] = el5 + r * 240000; er_r[r] = er5 + r * 240000; }
  u16* feats_d = feats;               // drug: 30000 x 384
  u16* feats_p = feats + 11520000;    // prot: 30000 x 256

  const dim3 blk(256);

  k_detect<<<dim3(1), dim3(64), 0, stream>>>(h_drug, flag);

  // rel order: 0=dd 1=pd 2=sd 3=dp 4=pp
  PJobs pj;
  pj.W[0]=W_dd; pj.al[0]=al_dd; pj.ar[0]=ar_dd;
  pj.W[1]=W_pd; pj.al[1]=al_pd; pj.ar[1]=ar_pd;
  pj.W[2]=W_sd; pj.al[2]=al_sd; pj.ar[2]=ar_sd;
  pj.W[3]=W_dp; pj.al[3]=al_dp; pj.ar[3]=ar_dp;
  pj.W[4]=W_pp; pj.al[4]=al_pp; pj.ar[4]=ar_pp;
  for (int r = 0; r < 5; ++r) { pj.wal[r] = wal[r]; pj.war[r] = war[r]; }
  k_prep_all<<<dim3(5), dim3(128), 0, stream>>>(pj, flag);

  KPack kp;
  kp.W[0]=W_dd; kp.W[1]=W_pd; kp.W[2]=W_sd; kp.W[3]=W_dp; kp.W[4]=W_pp; kp.W[5]=W1;
  for (int r = 0; r < 5; ++r) { kp.wal[r] = wal[r]; kp.war[r] = war[r]; }
  kp.wal[5]=nullptr; kp.war[5]=nullptr;
  for (int r = 0; r < 6; ++r) kp.out[r] = pk[r];
  k_pack_all<<<dim3(54), blk, 0, stream>>>(kp, flag);

  // ---- CSR build: hist -> bucketscan -> base -> bin -> fill2 (no atomics) ----
  EJobs ej;
  ej.src[0]=src_dd; ej.dst[0]=dst_dd;
  ej.src[1]=src_pd; ej.dst[1]=dst_pd;
  ej.src[2]=src_sd; ej.dst[2]=dst_sd;
  ej.src[3]=src_dp; ej.dst[3]=dst_dp;
  ej.src[4]=src_pp; ej.dst[4]=dst_pp;
  k_hist<<<dim3(NC), blk, 0, stream>>>(ej, ghist);
  k_bucketscan<<<dim3(NB), blk, 0, stream>>>(ghist, gcur, basep + NB + 1);
  k_base<<<dim3(1), dim3(1024), 0, stream>>>(basep + NB + 1, basep);
  k_bin<<<dim3(NC), blk, 0, stream>>>(ej, gcur, basep, bin);
  k_fill2<<<dim3(NB), blk, 0, stream>>>(bin, basep, csr, offsets);

  // ---- transforms (8 jobs, one launch) ----
  XJobs xj;
  auto setx = [&](int i, const void* x, const u16* bp, u16* z, float* el,
                  float* er, int N, int t0) {
    xj.x[i]=x; xj.bp[i]=bp; xj.z[i]=z; xj.el[i]=el; xj.er[i]=er; xj.N[i]=N; xj.t0[i]=t0;
  };
  setx(0, h_drug, pk[0], z_dd, el_r[0], er_r[0], ND, 0);   // dd
  setx(1, h_prot, pk[1], z_pd, el_r[1], nullptr, NP, 0);   // pd src
  setx(2, h_drug, pk[1], nullptr, nullptr, er_r[1], ND, 8);// pd dst
  setx(3, h_se,   pk[2], z_sd, el_r[2], nullptr, NS, 0);   // sd src
  setx(4, h_drug, pk[2], nullptr, nullptr, er_r[2], ND, 8);// sd dst
  setx(5, h_drug, pk[3], z_dp, el_r[3], nullptr, ND, 0);   // dp src
  setx(6, h_prot, pk[3], nullptr, nullptr, er_r[3], NP, 8);// dp dst
  setx(7, h_prot, pk[4], z_pp, el_r[4], er_r[4], NP, 0);   // pp
  {
    int acc = 0;
    for (int i = 0; i < 8; ++i) { xj.blk0[i] = acc; acc += (xj.N[i] + 63) / 64; }
    xj.blk0[8] = acc;
    k_xform_all<<<dim3(acc), blk, 0, stream>>>(xj, flag);
  }

  // ---- aggregation ----
  AJobs aj;
  const int ebase[5] = {0, 1000000, 2000000, 2500000, 3500000};
  const void* bias[5] = {b_dd, b_pd, b_sd, b_dp, b_pp};
  u16* fb[5] = {feats_d, feats_d + 128, feats_d + 256, feats_p, feats_p + 128};
  const int fstride[5] = {384, 384, 384, 256, 256};
  const u16* zz[5] = {z_dd, z_pd, z_sd, z_dp, z_pp};
  for (int r = 0; r < 5; ++r) {
    aj.csr[r] = csr + ebase[r];
    aj.off[r] = offsets + r * CSTRIDE;
    aj.el[r] = el_r[r];
    aj.er[r] = er_r[r];
    aj.z[r] = zz[r];
    aj.b[r] = bias[r];
    aj.feats[r] = fb[r];
    aj.stride[r] = fstride[r];
  }
  k_agg_all<<<dim3(150000 / 4), blk, 0, stream>>>(aj, flag);

  // ---- semantic attention + combine ----
  k_sem_all<<<dim3((150000 + 63) / 64), blk, 0, stream>>>(feats, pk[5], b1, W2, b2, s, 150000, flag);
  k_combine_all<<<dim3((7680000 + 255) / 256), blk, 0, stream>>>(feats, s, d_out, flag);
}

// Round 8
// 565.582 us; speedup vs baseline: 29.9869x; 1.0752x over previous
//
#include <hip/hip_runtime.h>
#include <hip/hip_bf16.h>

typedef unsigned short u16;
typedef __attribute__((ext_vector_type(8))) short short8;   // 8 bf16 (4 VGPRs)
typedef __attribute__((ext_vector_type(4))) float f32x4;

#define ND 30000
#define NP 30000
#define NS 10000
#define CSTRIDE 30016          // offsets per-relation stride (ints)
#define ETOT 4500000
#define CHUNK 9216             // edges per chunk (36 per thread)
#define NC 489                 // ceil(ETOT/CHUNK)
#define NBR 118                // buckets per relation (256 dsts each)
#define NB 590                 // total buckets

__device__ __forceinline__ float bf2f(u16 u) {
  union { unsigned int i; float f; } c; c.i = ((unsigned int)u) << 16; return c.f;
}
__device__ __forceinline__ u16 f2bf(float f) {
  union { float f; unsigned int i; } c; c.f = f;
  unsigned int u = c.i;
  unsigned int r = (u + 0x7fffu + ((u >> 16) & 1u)) >> 16;
  return (u16)r;
}

// Block-parallel input dtype detect (256 threads, ~1 us): for fp32 data the
// sampled u16s are mantissa halves (~16% sane exponent); bf16 ~100%.
__device__ __forceinline__ int detect_isbf(const void* x) {
  __shared__ int cnt4[4];
  const int tid = threadIdx.x;
  const u16 v = ((const u16*)x)[2 * tid];
  const int e = (v >> 7) & 0xff;
  const unsigned long long m = __ballot(e >= 100 && e <= 140);
  if ((tid & 63) == 0) cnt4[tid >> 6] = __popcll(m);
  __syncthreads();
  const int sane = cnt4[0] + cnt4[1] + cnt4[2] + cnt4[3];
  return sane >= 200;
}

__device__ __forceinline__ float ld_in(const void* p, int i, int isbf) {
  return isbf ? bf2f(((const u16*)p)[i]) : ((const float*)p)[i];
}

// ---------------------------------------------------------------------------
// Edge job tables
// ---------------------------------------------------------------------------
struct EJobs { const int* src[5]; const int* dst[5]; };
__device__ __forceinline__ int e_job(int e) {
  return (e >= 1000000) + (e >= 2000000) + (e >= 2500000) + (e >= 3500000);
}
__device__ __forceinline__ int e_base(int j) {
  const int base[6] = {0, 1000000, 2000000, 2500000, 3500000, 4500000};
  return base[j];
}

// ---------------------------------------------------------------------------
// prep: Wal[h][k] = sum_d W[k][h*16+d]*al[h*16+d] (and War with ar)
// ---------------------------------------------------------------------------
struct PJobs { const void* W[5]; const void* al[5]; const void* ar[5];
               float* wal[5]; float* war[5]; };
__device__ void prep_dev(const PJobs& J, int b, int isbf) {
  const int tid = threadIdx.x;
  if (tid >= 128) return;
  const int k = tid;
  for (int h = 0; h < 8; ++h) {
    float sa = 0.f, sr = 0.f;
    for (int d = 0; d < 16; ++d) {
      const float wv = ld_in(J.W[b], k * 128 + h * 16 + d, isbf);
      sa = fmaf(wv, ld_in(J.al[b], h * 16 + d, isbf), sa);
      sr = fmaf(wv, ld_in(J.ar[b], h * 16 + d, isbf), sr);
    }
    J.wal[b][h * 128 + k] = sa;
    J.war[b][h * 128 + k] = sr;
  }
}

// ---------------------------------------------------------------------------
// hist: per-chunk bucket histogram (LDS atomics only)
// ---------------------------------------------------------------------------
__device__ void hist_dev(const EJobs& J, int* __restrict__ ghist, int c) {
  __shared__ int hsh[NB];
  const int tid = threadIdx.x;
  for (int i = tid; i < NB; i += 256) hsh[i] = 0;
  __syncthreads();
  const int e0 = c * CHUNK;
  #pragma unroll 4
  for (int t = 0; t < 36; ++t) {
    const int e = e0 + t * 256 + tid;
    if (e < ETOT) {
      const int j = e_job(e);
      const int d = J.dst[j][e - e_base(j)];
      atomicAdd(&hsh[j * NBR + (d >> 8)], 1);
    }
  }
  __syncthreads();
  for (int i = tid; i < NB; i += 256) ghist[c * NB + i] = hsh[i];
}

// k_front: blocks 0..4 = prep, 5.. = hist
__global__ __launch_bounds__(256) void k_front(PJobs PJ, EJobs EJ,
    const void* xdet, int* __restrict__ ghist) {
  if (blockIdx.x < 5) {
    const int isbf = detect_isbf(xdet);
    prep_dev(PJ, blockIdx.x, isbf);
  } else {
    hist_dev(EJ, ghist, blockIdx.x - 5);
  }
}

// ---------------------------------------------------------------------------
// pack: B matrices into MFMA fragment order (jobs 0..4 = W|Wal|War, 5 = W1)
// ---------------------------------------------------------------------------
struct KPack { const void* W[6]; const float* wal[6]; const float* war[6];
               u16* out[6]; };
__device__ void pack_dev(const KPack& J, int b, int isbf) {
  const int job = b / 9;
  const int i0 = (b % 9) * 2048 + threadIdx.x * 8;
  const int kc = i0 / 4608;
  const int rem = i0 - kc * 4608;
  const int n = rem >> 5;
  const int q = (rem >> 3) & 3;
  u16 vals[8];
  #pragma unroll
  for (int j = 0; j < 8; ++j) {
    const int k = kc * 32 + q * 8 + j;
    float v;
    if (job == 5)      v = (n < 128) ? ld_in(J.W[5], k * 128 + n, isbf) : 0.f;
    else if (n < 128)  v = ld_in(J.W[job], k * 128 + n, isbf);
    else if (n < 136)  v = J.wal[job][(n - 128) * 128 + k];
    else               v = J.war[job][(n - 136) * 128 + k];
    vals[j] = f2bf(v);
  }
  *(uint4*)&J.out[job][i0] = *(uint4*)vals;
}

// bucketscan: per bucket, prefix over chunks
__device__ void bucketscan_dev(const int* __restrict__ ghist,
    int* __restrict__ gcur, int* __restrict__ totals, int b) {
  __shared__ int ts[256];
  const int tid = threadIdx.x;
  int v0 = 0, v1 = 0;
  const int c0 = tid * 2;
  if (c0 < NC) v0 = ghist[c0 * NB + b];
  if (c0 + 1 < NC) v1 = ghist[(c0 + 1) * NB + b];
  ts[tid] = v0 + v1;
  __syncthreads();
  for (int o = 1; o < 256; o <<= 1) {
    const int x = (tid >= o) ? ts[tid - o] : 0;
    __syncthreads();
    ts[tid] += x;
    __syncthreads();
  }
  int run = (tid == 0) ? 0 : ts[tid - 1];
  if (c0 < NC) { gcur[b * NC + c0] = run; run += v0; }
  if (c0 + 1 < NC) gcur[b * NC + c0 + 1] = run;
  if (tid == 255) totals[b] = ts[255];
}

// k_mid: blocks 0..53 = pack, 54.. = bucketscan
__global__ __launch_bounds__(256) void k_mid(KPack KJ, const void* xdet,
    const int* __restrict__ ghist, int* __restrict__ gcur, int* __restrict__ totals) {
  if (blockIdx.x < 54) {
    const int isbf = detect_isbf(xdet);
    pack_dev(KJ, blockIdx.x, isbf);
  } else {
    bucketscan_dev(ghist, gcur, totals, blockIdx.x - 54);
  }
}

// ---------------------------------------------------------------------------
// base prefix over the 590 bucket totals, recomputed in LDS (tiny)
// ---------------------------------------------------------------------------
__device__ void base_from_totals(const int* __restrict__ totals, int* bsh) {
  __shared__ int ts[256];
  const int tid = threadIdx.x;
  const int i0 = tid * 3;
  int v0 = 0, v1 = 0, v2 = 0;
  if (i0 < NB) v0 = totals[i0];
  if (i0 + 1 < NB) v1 = totals[i0 + 1];
  if (i0 + 2 < NB) v2 = totals[i0 + 2];
  ts[tid] = v0 + v1 + v2;
  __syncthreads();
  for (int o = 1; o < 256; o <<= 1) {
    const int x = (tid >= o) ? ts[tid - o] : 0;
    __syncthreads();
    ts[tid] += x;
    __syncthreads();
  }
  int run = (tid == 0) ? 0 : ts[tid - 1];
  if (i0 < NB) { bsh[i0] = run; run += v0; }
  if (i0 + 1 < NB) { bsh[i0 + 1] = run; run += v1; }
  if (i0 + 2 < NB) bsh[i0 + 2] = run;
  if (tid == 0) bsh[NB] = ETOT;
  __syncthreads();
}

// ---------------------------------------------------------------------------
// bin: scatter (dst&255 | src) into bucket-ordered runs (LDS cursors)
// ---------------------------------------------------------------------------
__global__ __launch_bounds__(256) void k_bin(EJobs J,
    const int* __restrict__ gcur, const int* __restrict__ totals,
    unsigned int* __restrict__ bin) {
  __shared__ int bsh[NB + 1];
  __shared__ int cur[NB];
  base_from_totals(totals, bsh);
  const int c = blockIdx.x, tid = threadIdx.x;
  for (int i = tid; i < NB; i += 256) cur[i] = bsh[i] + gcur[i * NC + c];
  __syncthreads();
  const int e0 = c * CHUNK;
  #pragma unroll 4
  for (int t = 0; t < 36; ++t) {
    const int e = e0 + t * 256 + tid;
    if (e < ETOT) {
      const int j = e_job(e);
      const int le = e - e_base(j);
      const int d = J.dst[j][le];
      const int s = J.src[j][le];
      const int pos = atomicAdd(&cur[j * NBR + (d >> 8)], 1);
      bin[pos] = ((unsigned int)(d & 255) << 16) | (unsigned int)s;
    }
  }
}

// ---------------------------------------------------------------------------
// fill2: per bucket, sort 256 dsts in LDS, emit u16 CSR + offsets
// ---------------------------------------------------------------------------
__device__ void fill2_dev(const unsigned int* __restrict__ bin,
    const int* __restrict__ totals, u16* __restrict__ csr,
    int* __restrict__ offsets, int b) {
  __shared__ int bsh2[NB + 1];
  __shared__ int cnt[256], curs[256];
  base_from_totals(totals, bsh2);
  const int tid = threadIdx.x;
  const int rel = b / NBR;
  const int bloc = b - rel * NBR;
  const int d0 = bloc << 8;
  const int gbeg = bsh2[b];
  const int n = bsh2[b + 1] - gbeg;
  cnt[tid] = 0;
  __syncthreads();
  for (int i = tid; i < n; i += 256)
    atomicAdd(&cnt[bin[gbeg + i] >> 16], 1);
  __syncthreads();
  const int orig = cnt[tid];
  for (int o = 1; o < 256; o <<= 1) {
    const int x = (tid >= o) ? cnt[tid - o] : 0;
    __syncthreads();
    cnt[tid] += x;
    __syncthreads();
  }
  const int ex = cnt[tid] - orig;
  curs[tid] = ex;
  const int ebr = e_base(rel);
  const int d = d0 + tid;
  if (d < 30000) offsets[rel * CSTRIDE + d] = (gbeg - ebr) + ex;
  if (bloc == NBR - 1 && tid == 0)
    offsets[rel * CSTRIDE + 30000] = e_base(rel + 1) - ebr;
  __syncthreads();
  for (int i = tid; i < n; i += 256) {
    const unsigned int v = bin[gbeg + i];
    const int pos = atomicAdd(&curs[v >> 16], 1);
    csr[gbeg + pos] = (u16)(v & 0xffffu);
  }
}

// ---------------------------------------------------------------------------
// MFMA transform (R6-proven): [Nx128]@[128x144]; tiles 0..7->z, 8->el/er
// ---------------------------------------------------------------------------
struct XJobs {
  const void* x[8]; const u16* bp[8]; u16* z[8]; float* el[8]; float* er[8];
  int N[8]; int t0[8]; int blk0[9];
};
__device__ void xform_dev(const XJobs& J, int xb, int isbf) {
  __shared__ __align__(16) u16 Bf[18432];
  __shared__ __align__(16) u16 As[64 * 136];
  const int tid = threadIdx.x;
  int job = 0;
  while (xb >= J.blk0[job + 1]) ++job;
  const int row0 = (xb - J.blk0[job]) * 64;
  const int N = J.N[job];
  const int t0 = J.t0[job];
  const u16* bp = J.bp[job];
  const void* x = J.x[job];

  if (t0 == 0) {
    for (int i = tid * 8; i < 18432; i += 2048)
      *(uint4*)&Bf[i] = *(const uint4*)&bp[i];
  } else {
    const int i = tid * 8;
    const int kc = i >> 9;
    const int off = (kc * 144 + 128) * 32 + (i & 511);
    *(uint4*)&Bf[off] = *(const uint4*)&bp[off];
  }

  if (isbf) {
    const uint4* xv = (const uint4*)x;
    for (int i = tid; i < 1024; i += 256) {
      const int r = i >> 4, c8 = i & 15;
      const int row = row0 + r;
      uint4 v = make_uint4(0, 0, 0, 0);
      if (row < N) v = xv[row * 16 + c8];
      *(uint4*)&As[r * 136 + c8 * 8] = v;
    }
  } else {
    const float4* xf = (const float4*)x;
    for (int i = tid; i < 2048; i += 256) {
      const int r = i >> 5, c4 = i & 31;
      const int row = row0 + r;
      unsigned long long pkv = 0ull;
      if (row < N) {
        const float4 v = xf[row * 32 + c4];
        pkv = (unsigned long long)f2bf(v.x) | ((unsigned long long)f2bf(v.y) << 16)
            | ((unsigned long long)f2bf(v.z) << 32) | ((unsigned long long)f2bf(v.w) << 48);
      }
      *(unsigned long long*)&As[r * 136 + c4 * 4] = pkv;
    }
  }
  __syncthreads();

  const int wave = tid >> 6;
  const int lane = tid & 63;
  const int q = lane >> 4;
  const int c = lane & 15;

  f32x4 accT[8];
  f32x4 acc8 = (f32x4){0.f, 0.f, 0.f, 0.f};
  if (t0 == 0) {
    #pragma unroll
    for (int t = 0; t < 8; ++t) accT[t] = (f32x4){0.f, 0.f, 0.f, 0.f};
  }

  #pragma unroll
  for (int kc = 0; kc < 4; ++kc) {
    const short8 a = *(const short8*)&As[(wave * 16 + c) * 136 + kc * 32 + q * 8];
    if (t0 == 0) {
      #pragma unroll
      for (int t = 0; t < 8; ++t) {
        const short8 bb = *(const short8*)&Bf[((kc * 144 + t * 16 + c) * 4 + q) * 8];
        accT[t] = __builtin_amdgcn_mfma_f32_16x16x32_bf16(a, bb, accT[t], 0, 0, 0);
      }
    }
    const short8 b8 = *(const short8*)&Bf[((kc * 144 + 128 + c) * 4 + q) * 8];
    acc8 = __builtin_amdgcn_mfma_f32_16x16x32_bf16(a, b8, acc8, 0, 0, 0);
  }

  const int rbase = row0 + wave * 16 + q * 4;
  if (t0 == 0 && J.z[job]) {
    u16* zo = J.z[job];
    #pragma unroll
    for (int t = 0; t < 8; ++t)
      #pragma unroll
      for (int r = 0; r < 4; ++r) {
        const int row = rbase + r;
        if (row < N) zo[row * 128 + t * 16 + c] = f2bf(accT[t][r]);
      }
  }
  #pragma unroll
  for (int r = 0; r < 4; ++r) {
    const int row = rbase + r;
    if (row < N) {
      const float v = acc8[r];
      if (c < 8) { if (J.el[job]) J.el[job][row * 8 + c] = v; }
      else       { if (J.er[job]) J.er[job][row * 8 + (c - 8)] = v; }
    }
  }
}

// k_l4: blocks 0..589 = fill2, 590.. = xform
__global__ __launch_bounds__(256) void k_l4(XJobs XJ, const void* xdet,
    const unsigned int* __restrict__ bin, const int* __restrict__ totals,
    u16* __restrict__ csr, int* __restrict__ offsets) {
  if (blockIdx.x < NB) {
    fill2_dev(bin, totals, csr, offsets, blockIdx.x);
  } else {
    const int isbf = detect_isbf(xdet);
    xform_dev(XJ, blockIdx.x - NB, isbf);
  }
}

// ---------------------------------------------------------------------------
// Aggregation: one wave per (relation, dst). 8 edges/iter; lane (h,i)
// computes ex(edge i, head h) exactly once; s_i broadcast via readlane
// (SGPR z-base), ex_i via ds_bpermute (LDS pipe). den reduced at end.
// ---------------------------------------------------------------------------
struct AJobs { const u16* csr[5]; const int* off[5]; const float* el[5];
               const float* er[5]; const u16* z[5]; const void* b[5];
               u16* feats[5]; int stride[5]; };
__global__ __launch_bounds__(256) void k_agg_all(AJobs J, const void* xdet) {
  const int isbf = detect_isbf(xdet);
  const int gw = (blockIdx.x * 256 + threadIdx.x) >> 6;
  const int lane = threadIdx.x & 63;
  const int job = gw / 30000;
  const int d = gw - job * 30000;
  const int h = lane >> 3;            // head of this lane's feature pair
  const int i8 = lane & 7;            // which of 8 edges this lane exps
  const float* el = J.el[job];
  const u16* z = J.z[job];
  const u16* csr = J.csr[job];
  const float erh = J.er[job][d * 8 + h];
  const int beg = J.off[job][d];
  const int end = J.off[job][d + 1];
  const int gb4 = (lane & 56) << 2;   // bpermute byte base of this h-group

  float a0 = 0.f, a1 = 0.f, denP = 0.f;
  int p = beg;
  for (; p + 8 <= end; p += 8) {
    const int sE = (int)csr[p + i8];
    float eh = el[sE * 8 + h] + erh;
    eh = fminf(fmaxf(eh, 0.2f * eh), 60.f);   // leaky_relu + clamp
    const float exE = __expf(eh);
    denP += exE;
    const int exbits = __float_as_int(exE);
    #pragma unroll
    for (int i = 0; i < 8; ++i) {
      const int si = __builtin_amdgcn_readlane(sE, i);
      const float exi = __int_as_float(
          __builtin_amdgcn_ds_bpermute(gb4 + i * 4, exbits));
      const unsigned int zp = *(const unsigned int*)(z + si * 128 + lane * 2);
      union { unsigned int u; float f; } lo, hi;
      lo.u = zp << 16; hi.u = zp & 0xffff0000u;
      a0 = fmaf(exi, lo.f, a0);
      a1 = fmaf(exi, hi.f, a1);
    }
  }
  if (p < end) {
    const int r = end - p;
    int sE = 0; float exE = 0.f;
    if (i8 < r) {
      sE = (int)csr[p + i8];
      float eh = el[sE * 8 + h] + erh;
      eh = fminf(fmaxf(eh, 0.2f * eh), 60.f);
      exE = __expf(eh);
    }
    denP += exE;
    const int exbits = __float_as_int(exE);
    for (int i = 0; i < r; ++i) {
      const int si = __builtin_amdgcn_readlane(sE, i);
      const float exi = __int_as_float(
          __builtin_amdgcn_ds_bpermute(gb4 + i * 4, exbits));
      const unsigned int zp = *(const unsigned int*)(z + si * 128 + lane * 2);
      union { unsigned int u; float f; } lo, hi;
      lo.u = zp << 16; hi.u = zp & 0xffff0000u;
      a0 = fmaf(exi, lo.f, a0);
      a1 = fmaf(exi, hi.f, a1);
    }
  }
  denP += __shfl_xor(denP, 1);
  denP += __shfl_xor(denP, 2);
  denP += __shfl_xor(denP, 4);        // full den(h) within the 8-lane group
  const float inv = 1.f / fmaxf(denP, 1e-9f);
  const int j0 = lane * 2;
  const float v0 = a0 * inv + ld_in(J.b[job], j0, isbf);
  const float v1 = a1 * inv + ld_in(J.b[job], j0 + 1, isbf);
  const unsigned int packed = (unsigned int)f2bf(v0) | ((unsigned int)f2bf(v1) << 16);
  *(unsigned int*)(J.feats[job] + d * J.stride[job] + j0) = packed;
}

// ---------------------------------------------------------------------------
// MFMA semantic score (R6-proven) + inline detect
// ---------------------------------------------------------------------------
__global__ __launch_bounds__(256) void k_sem_all(
    const u16* __restrict__ f, const u16* __restrict__ w1pack,
    const void* __restrict__ b1, const void* __restrict__ W2,
    const void* __restrict__ b2, float* __restrict__ s_out, int total,
    const void* xdet)
{
  __shared__ __align__(16) u16 Bf[18432];
  __shared__ __align__(16) u16 As[64 * 136];
  __shared__ float b1S[128], W2S[128];
  const int isbf = detect_isbf(xdet);
  const int tid = threadIdx.x;
  const int row0 = blockIdx.x * 64;

  for (int i = tid * 8; i < 18432; i += 2048)
    *(uint4*)&Bf[i] = *(const uint4*)&w1pack[i];
  if (tid < 128) { b1S[tid] = ld_in(b1, tid, isbf); W2S[tid] = ld_in(W2, tid, isbf); }
  {
    const uint4* xv = (const uint4*)f;
    for (int i = tid; i < 1024; i += 256) {
      const int r = i >> 4, c8 = i & 15;
      const int row = row0 + r;
      uint4 v = make_uint4(0, 0, 0, 0);
      if (row < total) v = xv[row * 16 + c8];
      *(uint4*)&As[r * 136 + c8 * 8] = v;
    }
  }
  __syncthreads();

  const int wave = tid >> 6;
  const int lane = tid & 63;
  const int q = lane >> 4;
  const int c = lane & 15;

  f32x4 acc[8];
  #pragma unroll
  for (int t = 0; t < 8; ++t) acc[t] = (f32x4){0.f, 0.f, 0.f, 0.f};

  #pragma unroll
  for (int kc = 0; kc < 4; ++kc) {
    const short8 a = *(const short8*)&As[(wave * 16 + c) * 136 + kc * 32 + q * 8];
    #pragma unroll
    for (int t = 0; t < 8; ++t) {
      const short8 bb = *(const short8*)&Bf[((kc * 144 + t * 16 + c) * 4 + q) * 8];
      acc[t] = __builtin_amdgcn_mfma_f32_16x16x32_bf16(a, bb, acc[t], 0, 0, 0);
    }
  }

  float part[4] = {0.f, 0.f, 0.f, 0.f};
  #pragma unroll
  for (int t = 0; t < 8; ++t) {
    const int n = t * 16 + c;
    const float b1v = b1S[n];
    const float w2v = W2S[n];
    #pragma unroll
    for (int r = 0; r < 4; ++r) {
      const float hv = acc[t][r] + b1v;
      const float e = __expf(2.f * hv);
      const float th = 1.f - 2.f / (e + 1.f);
      part[r] = fmaf(th, w2v, part[r]);
    }
  }
  #pragma unroll
  for (int r = 0; r < 4; ++r) {
    part[r] += __shfl_xor(part[r], 1);
    part[r] += __shfl_xor(part[r], 2);
    part[r] += __shfl_xor(part[r], 4);
    part[r] += __shfl_xor(part[r], 8);
  }
  if (c == 0) {
    const float b2v = ld_in(b2, 0, isbf);
    #pragma unroll
    for (int r = 0; r < 4; ++r) {
      const int row = row0 + wave * 16 + q * 4 + r;
      if (row < total) s_out[row] = part[r] + b2v;
    }
  }
}

// ---------------------------------------------------------------------------
// Combine (R6-proven) + inline detect
// ---------------------------------------------------------------------------
__global__ __launch_bounds__(256) void k_combine_all(
    const u16* __restrict__ feats, const float* __restrict__ s,
    void* __restrict__ out, const void* xdet)
{
  const int isbf = detect_isbf(xdet);
  const int i = blockIdx.x * 256 + threadIdx.x;
  if (i >= 7680000) return;
  const bool drug = (i < 3840000);
  const int li = drug ? i : i - 3840000;
  const int n = li >> 7;
  const int j = li & 127;
  const float* sr = s + (drug ? n * 3 : 90000 + n * 2);
  const u16* fb = feats + (drug ? n * 384 : 11520000 + n * 256);
  const float s0v = sr[0];
  const float s1v = sr[1];
  const float s2v = drug ? sr[2] : -3.4e38f;
  const float m = fmaxf(fmaxf(s0v, s1v), s2v);
  const float w0 = __expf(s0v - m);
  const float w1 = __expf(s1v - m);
  const float w2 = drug ? __expf(s2v - m) : 0.f;
  const float inv = 1.f / (w0 + w1 + w2);
  float acc = w0 * bf2f(fb[j]) + w1 * bf2f(fb[128 + j]);
  if (drug) acc += w2 * bf2f(fb[256 + j]);
  const float v = acc * inv;
  if (isbf) ((u16*)out)[i] = f2bf(v);
  else      ((float*)out)[i] = v;
}

extern "C" void kernel_launch(void* const* d_in, const int* in_sizes, int n_in,
                              void* d_out, int out_size, void* d_ws, size_t ws_size,
                              hipStream_t stream)
{
  (void)in_sizes; (void)n_in; (void)out_size; (void)ws_size;

  const void* h_drug = d_in[0];
  const void* h_prot = d_in[1];
  const void* h_se   = d_in[2];
  const void* W_dd = d_in[3];  const void* al_dd = d_in[4];
  const void* ar_dd = d_in[5]; const void* b_dd  = d_in[6];
  const void* W_dp = d_in[7];  const void* al_dp = d_in[8];
  const void* ar_dp = d_in[9]; const void* b_dp  = d_in[10];
  const void* W_pd = d_in[11]; const void* al_pd = d_in[12];
  const void* ar_pd = d_in[13];const void* b_pd  = d_in[14];
  const void* W_pp = d_in[15]; const void* al_pp = d_in[16];
  const void* ar_pp = d_in[17];const void* b_pp  = d_in[18];
  const void* W_sd = d_in[19]; const void* al_sd = d_in[20];
  const void* ar_sd = d_in[21];const void* b_sd  = d_in[22];
  const void* W1 = d_in[23];   const void* b1 = d_in[24];
  const void* W2 = d_in[25];   const void* b2 = d_in[26];
  const int* src_dd = (const int*)d_in[27];
  const int* dst_dd = (const int*)d_in[28];
  const int* src_dp = (const int*)d_in[29];
  const int* dst_dp = (const int*)d_in[30];
  const int* src_pd = (const int*)d_in[31];
  const int* dst_pd = (const int*)d_in[32];
  const int* src_pp = (const int*)d_in[33];
  const int* dst_pp = (const int*)d_in[34];
  const int* src_sd = (const int*)d_in[35];
  const int* dst_sd = (const int*)d_in[36];

  // ---- workspace layout (~94.1 MB <= 101.4 MB proven in R6) ----
  char* w = (char*)d_ws;
  float* el5   = (float*)(w);                    // 4,800,000
  float* er5   = (float*)(w + 4800000);          // 4,800,000
  u16* z_dd    = (u16*)(w + 9600000);            // 7,680,000
  u16* z_pd    = (u16*)(w + 17280000);           // 7,680,000
  u16* z_sd    = (u16*)(w + 24960000);           // 2,560,000
  u16* z_dp    = (u16*)(w + 27520000);           // 7,680,000
  u16* z_pp    = (u16*)(w + 35200000);           // 7,680,000
  int* offsets = (int*)(w + 42880000);           // 600,320
  u16* csr     = (u16*)(w + 43480320);           // 9,000,000
  int* ghist   = (int*)(w + 52480320);           // 1,154,040
  int* gcur    = (int*)(w + 53634560);           // 1,154,040
  int* totals  = (int*)(w + 54788608);           // 2,360
  float* s     = (float*)(w + 54791168);         // 600,000
  u16* feats   = (u16*)(w + 55391232);           // 38,400,000 (16B aligned)
  unsigned int* bin = (unsigned int*)(w + 55391232); // aliases feats (dead before agg)
  float* ww    = (float*)(w + 93791232);         // 40,960 (wal/war x5)
  u16* packs   = (u16*)(w + 93832192);           // 221,184 -> end 94,053,376

  float *wal[5], *war[5];
  for (int r = 0; r < 5; ++r) { wal[r] = ww + r * 2048; war[r] = ww + r * 2048 + 1024; }
  u16* pk[6];
  for (int r = 0; r < 6; ++r) pk[r] = packs + r * 18432;
  float* el_r[5]; float* er_r[5];
  for (int r = 0; r < 5; ++r) { el_r[r] = el5 + r * 240000; er_r[r] = er5 + r * 240000; }
  u16* feats_d = feats;               // drug: 30000 x 384
  u16* feats_p = feats + 11520000;    // prot: 30000 x 256

  const dim3 blk(256);

  // rel order: 0=dd 1=pd 2=sd 3=dp 4=pp
  PJobs pj;
  pj.W[0]=W_dd; pj.al[0]=al_dd; pj.ar[0]=ar_dd;
  pj.W[1]=W_pd; pj.al[1]=al_pd; pj.ar[1]=ar_pd;
  pj.W[2]=W_sd; pj.al[2]=al_sd; pj.ar[2]=ar_sd;
  pj.W[3]=W_dp; pj.al[3]=al_dp; pj.ar[3]=ar_dp;
  pj.W[4]=W_pp; pj.al[4]=al_pp; pj.ar[4]=ar_pp;
  for (int r = 0; r < 5; ++r) { pj.wal[r] = wal[r]; pj.war[r] = war[r]; }

  EJobs ej;
  ej.src[0]=src_dd; ej.dst[0]=dst_dd;
  ej.src[1]=src_pd; ej.dst[1]=dst_pd;
  ej.src[2]=src_sd; ej.dst[2]=dst_sd;
  ej.src[3]=src_dp; ej.dst[3]=dst_dp;
  ej.src[4]=src_pp; ej.dst[4]=dst_pp;

  KPack kp;
  kp.W[0]=W_dd; kp.W[1]=W_pd; kp.W[2]=W_sd; kp.W[3]=W_dp; kp.W[4]=W_pp; kp.W[5]=W1;
  for (int r = 0; r < 5; ++r) { kp.wal[r] = wal[r]; kp.war[r] = war[r]; }
  kp.wal[5]=nullptr; kp.war[5]=nullptr;
  for (int r = 0; r < 6; ++r) kp.out[r] = pk[r];

  XJobs xj;
  auto setx = [&](int i, const void* x, const u16* bp, u16* z, float* el,
                  float* er, int N, int t0) {
    xj.x[i]=x; xj.bp[i]=bp; xj.z[i]=z; xj.el[i]=el; xj.er[i]=er; xj.N[i]=N; xj.t0[i]=t0;
  };
  setx(0, h_drug, pk[0], z_dd, el_r[0], er_r[0], ND, 0);   // dd
  setx(1, h_prot, pk[1], z_pd, el_r[1], nullptr, NP, 0);   // pd src
  setx(2, h_drug, pk[1], nullptr, nullptr, er_r[1], ND, 8);// pd dst
  setx(3, h_se,   pk[2], z_sd, el_r[2], nullptr, NS, 0);   // sd src
  setx(4, h_drug, pk[2], nullptr, nullptr, er_r[2], ND, 8);// sd dst
  setx(5, h_drug, pk[3], z_dp, el_r[3], nullptr, ND, 0);   // dp src
  setx(6, h_prot, pk[3], nullptr, nullptr, er_r[3], NP, 8);// dp dst
  setx(7, h_prot, pk[4], z_pp, el_r[4], er_r[4], NP, 0);   // pp
  int xblocks = 0;
  for (int i = 0; i < 8; ++i) { xj.blk0[i] = xblocks; xblocks += (xj.N[i] + 63) / 64; }
  xj.blk0[8] = xblocks;

  AJobs aj;
  const int ebase[5] = {0, 1000000, 2000000, 2500000, 3500000};
  const void* bias[5] = {b_dd, b_pd, b_sd, b_dp, b_pp};
  u16* fb[5] = {feats_d, feats_d + 128, feats_d + 256, feats_p, feats_p + 128};
  const int fstride[5] = {384, 384, 384, 256, 256};
  const u16* zz[5] = {z_dd, z_pd, z_sd, z_dp, z_pp};
  for (int r = 0; r < 5; ++r) {
    aj.csr[r] = csr + ebase[r];
    aj.off[r] = offsets + r * CSTRIDE;
    aj.el[r] = el_r[r];
    aj.er[r] = er_r[r];
    aj.z[r] = zz[r];
    aj.b[r] = bias[r];
    aj.feats[r] = fb[r];
    aj.stride[r] = fstride[r];
  }

  // ---- 7 launches, no memsets ----
  k_front<<<dim3(5 + NC), blk, 0, stream>>>(pj, ej, h_drug, ghist);
  k_mid<<<dim3(54 + NB), blk, 0, stream>>>(kp, h_drug, ghist, gcur, totals);
  k_bin<<<dim3(NC), blk, 0, stream>>>(ej, gcur, totals, bin);
  k_l4<<<dim3(NB + xblocks), blk, 0, stream>>>(xj, h_drug, bin, totals, csr, offsets);
  k_agg_all<<<dim3(37500), blk, 0, stream>>>(aj, h_drug);
  k_sem_all<<<dim3((150000 + 63) / 64), blk, 0, stream>>>(feats, pk[5], b1, W2, b2, s, 150000, h_drug);
  k_combine_all<<<dim3(30000), blk, 0, stream>>>(feats, s, d_out, h_drug);
}

// Round 9
// 543.049 us; speedup vs baseline: 31.2312x; 1.0415x over previous
//
#include <hip/hip_runtime.h>
#include <hip/hip_bf16.h>

typedef unsigned short u16;
typedef __attribute__((ext_vector_type(8))) short short8;   // 8 bf16 (4 VGPRs)
typedef __attribute__((ext_vector_type(4))) float f32x4;

#define ND 30000
#define NP 30000
#define NS 10000
#define CSTRIDE 30016          // offsets per-relation stride (ints)
#define ETOT 4500000
#define CHUNK 9216             // edges per chunk (36 per thread)
#define NC 489                 // ceil(ETOT/CHUNK)
#define NBR 118                // buckets per relation (256 dsts each)
#define NB 590                 // total buckets

__device__ __forceinline__ float bf2f(u16 u) {
  union { unsigned int i; float f; } c; c.i = ((unsigned int)u) << 16; return c.f;
}
__device__ __forceinline__ u16 f2bf(float f) {
  union { float f; unsigned int i; } c; c.f = f;
  unsigned int u = c.i;
  unsigned int r = (u + 0x7fffu + ((u >> 16) & 1u)) >> 16;
  return (u16)r;
}

// Block-parallel input dtype detect (256 threads, ~1 us): for fp32 data the
// sampled u16s are mantissa halves (~16% sane exponent); bf16 ~100%.
__device__ __forceinline__ int detect_isbf(const void* x) {
  __shared__ int cnt4[4];
  const int tid = threadIdx.x;
  const u16 v = ((const u16*)x)[2 * tid];
  const int e = (v >> 7) & 0xff;
  const unsigned long long m = __ballot(e >= 100 && e <= 140);
  if ((tid & 63) == 0) cnt4[tid >> 6] = __popcll(m);
  __syncthreads();
  const int sane = cnt4[0] + cnt4[1] + cnt4[2] + cnt4[3];
  return sane >= 200;
}

__device__ __forceinline__ float ld_in(const void* p, int i, int isbf) {
  return isbf ? bf2f(((const u16*)p)[i]) : ((const float*)p)[i];
}

// ---------------------------------------------------------------------------
// Edge job tables
// ---------------------------------------------------------------------------
struct EJobs { const int* src[5]; const int* dst[5]; };
__device__ __forceinline__ int e_job(int e) {
  return (e >= 1000000) + (e >= 2000000) + (e >= 2500000) + (e >= 3500000);
}
__device__ __forceinline__ int e_base(int j) {
  const int base[6] = {0, 1000000, 2000000, 2500000, 3500000, 4500000};
  return base[j];
}

// ---------------------------------------------------------------------------
// prep: Wal[h][k] = sum_d W[k][h*16+d]*al[h*16+d] (and War with ar)
// ---------------------------------------------------------------------------
struct PJobs { const void* W[5]; const void* al[5]; const void* ar[5];
               float* wal[5]; float* war[5]; };
__device__ void prep_dev(const PJobs& J, int b, int isbf) {
  const int tid = threadIdx.x;
  if (tid >= 128) return;
  const int k = tid;
  for (int h = 0; h < 8; ++h) {
    float sa = 0.f, sr = 0.f;
    for (int d = 0; d < 16; ++d) {
      const float wv = ld_in(J.W[b], k * 128 + h * 16 + d, isbf);
      sa = fmaf(wv, ld_in(J.al[b], h * 16 + d, isbf), sa);
      sr = fmaf(wv, ld_in(J.ar[b], h * 16 + d, isbf), sr);
    }
    J.wal[b][h * 128 + k] = sa;
    J.war[b][h * 128 + k] = sr;
  }
}

// ---------------------------------------------------------------------------
// hist: per-chunk bucket histogram (LDS atomics only)
// ---------------------------------------------------------------------------
__device__ void hist_dev(const EJobs& J, int* __restrict__ ghist, int c) {
  __shared__ int hsh[NB];
  const int tid = threadIdx.x;
  for (int i = tid; i < NB; i += 256) hsh[i] = 0;
  __syncthreads();
  const int e0 = c * CHUNK;
  #pragma unroll 4
  for (int t = 0; t < 36; ++t) {
    const int e = e0 + t * 256 + tid;
    if (e < ETOT) {
      const int j = e_job(e);
      const int d = J.dst[j][e - e_base(j)];
      atomicAdd(&hsh[j * NBR + (d >> 8)], 1);
    }
  }
  __syncthreads();
  for (int i = tid; i < NB; i += 256) ghist[c * NB + i] = hsh[i];
}

// k_front: blocks 0..4 = prep, 5.. = hist
__global__ __launch_bounds__(256) void k_front(PJobs PJ, EJobs EJ,
    const void* xdet, int* __restrict__ ghist) {
  if (blockIdx.x < 5) {
    const int isbf = detect_isbf(xdet);
    prep_dev(PJ, blockIdx.x, isbf);
  } else {
    hist_dev(EJ, ghist, blockIdx.x - 5);
  }
}

// ---------------------------------------------------------------------------
// pack: B matrices into MFMA fragment order (jobs 0..4 = W|Wal|War, 5 = W1)
// ---------------------------------------------------------------------------
struct KPack { const void* W[6]; const float* wal[6]; const float* war[6];
               u16* out[6]; };
__device__ void pack_dev(const KPack& J, int b, int isbf) {
  const int job = b / 9;
  const int i0 = (b % 9) * 2048 + threadIdx.x * 8;
  const int kc = i0 / 4608;
  const int rem = i0 - kc * 4608;
  const int n = rem >> 5;
  const int q = (rem >> 3) & 3;
  u16 vals[8];
  #pragma unroll
  for (int j = 0; j < 8; ++j) {
    const int k = kc * 32 + q * 8 + j;
    float v;
    if (job == 5)      v = (n < 128) ? ld_in(J.W[5], k * 128 + n, isbf) : 0.f;
    else if (n < 128)  v = ld_in(J.W[job], k * 128 + n, isbf);
    else if (n < 136)  v = J.wal[job][(n - 128) * 128 + k];
    else               v = J.war[job][(n - 136) * 128 + k];
    vals[j] = f2bf(v);
  }
  *(uint4*)&J.out[job][i0] = *(uint4*)vals;
}

// bucketscan: per bucket, prefix over chunks
__device__ void bucketscan_dev(const int* __restrict__ ghist,
    int* __restrict__ gcur, int* __restrict__ totals, int b) {
  __shared__ int ts[256];
  const int tid = threadIdx.x;
  int v0 = 0, v1 = 0;
  const int c0 = tid * 2;
  if (c0 < NC) v0 = ghist[c0 * NB + b];
  if (c0 + 1 < NC) v1 = ghist[(c0 + 1) * NB + b];
  ts[tid] = v0 + v1;
  __syncthreads();
  for (int o = 1; o < 256; o <<= 1) {
    const int x = (tid >= o) ? ts[tid - o] : 0;
    __syncthreads();
    ts[tid] += x;
    __syncthreads();
  }
  int run = (tid == 0) ? 0 : ts[tid - 1];
  if (c0 < NC) { gcur[b * NC + c0] = run; run += v0; }
  if (c0 + 1 < NC) gcur[b * NC + c0 + 1] = run;
  if (tid == 255) totals[b] = ts[255];
}

// k_mid: blocks 0..53 = pack, 54.. = bucketscan
__global__ __launch_bounds__(256) void k_mid(KPack KJ, const void* xdet,
    const int* __restrict__ ghist, int* __restrict__ gcur, int* __restrict__ totals) {
  if (blockIdx.x < 54) {
    const int isbf = detect_isbf(xdet);
    pack_dev(KJ, blockIdx.x, isbf);
  } else {
    bucketscan_dev(ghist, gcur, totals, blockIdx.x - 54);
  }
}

// ---------------------------------------------------------------------------
// base prefix over the 590 bucket totals, recomputed in LDS (tiny)
// ---------------------------------------------------------------------------
__device__ void base_from_totals(const int* __restrict__ totals, int* bsh) {
  __shared__ int ts[256];
  const int tid = threadIdx.x;
  const int i0 = tid * 3;
  int v0 = 0, v1 = 0, v2 = 0;
  if (i0 < NB) v0 = totals[i0];
  if (i0 + 1 < NB) v1 = totals[i0 + 1];
  if (i0 + 2 < NB) v2 = totals[i0 + 2];
  ts[tid] = v0 + v1 + v2;
  __syncthreads();
  for (int o = 1; o < 256; o <<= 1) {
    const int x = (tid >= o) ? ts[tid - o] : 0;
    __syncthreads();
    ts[tid] += x;
    __syncthreads();
  }
  int run = (tid == 0) ? 0 : ts[tid - 1];
  if (i0 < NB) { bsh[i0] = run; run += v0; }
  if (i0 + 1 < NB) { bsh[i0 + 1] = run; run += v1; }
  if (i0 + 2 < NB) bsh[i0 + 2] = run;
  if (tid == 0) bsh[NB] = ETOT;
  __syncthreads();
}

// ---------------------------------------------------------------------------
// bin: scatter (dst&255 | src) into bucket-ordered runs (LDS cursors)
// ---------------------------------------------------------------------------
__global__ __launch_bounds__(256) void k_bin(EJobs J,
    const int* __restrict__ gcur, const int* __restrict__ totals,
    unsigned int* __restrict__ bin) {
  __shared__ int bsh[NB + 1];
  __shared__ int cur[NB];
  base_from_totals(totals, bsh);
  const int c = blockIdx.x, tid = threadIdx.x;
  for (int i = tid; i < NB; i += 256) cur[i] = bsh[i] + gcur[i * NC + c];
  __syncthreads();
  const int e0 = c * CHUNK;
  #pragma unroll 4
  for (int t = 0; t < 36; ++t) {
    const int e = e0 + t * 256 + tid;
    if (e < ETOT) {
      const int j = e_job(e);
      const int le = e - e_base(j);
      const int d = J.dst[j][le];
      const int s = J.src[j][le];
      const int pos = atomicAdd(&cur[j * NBR + (d >> 8)], 1);
      bin[pos] = ((unsigned int)(d & 255) << 16) | (unsigned int)s;
    }
  }
}

// ---------------------------------------------------------------------------
// fill2: per bucket, sort 256 dsts in LDS, emit u16 CSR + offsets
// ---------------------------------------------------------------------------
__device__ void fill2_dev(const unsigned int* __restrict__ bin,
    const int* __restrict__ totals, u16* __restrict__ csr,
    int* __restrict__ offsets, int b) {
  __shared__ int bsh2[NB + 1];
  __shared__ int cnt[256], curs[256];
  base_from_totals(totals, bsh2);
  const int tid = threadIdx.x;
  const int rel = b / NBR;
  const int bloc = b - rel * NBR;
  const int d0 = bloc << 8;
  const int gbeg = bsh2[b];
  const int n = bsh2[b + 1] - gbeg;
  cnt[tid] = 0;
  __syncthreads();
  for (int i = tid; i < n; i += 256)
    atomicAdd(&cnt[bin[gbeg + i] >> 16], 1);
  __syncthreads();
  const int orig = cnt[tid];
  for (int o = 1; o < 256; o <<= 1) {
    const int x = (tid >= o) ? cnt[tid - o] : 0;
    __syncthreads();
    cnt[tid] += x;
    __syncthreads();
  }
  const int ex = cnt[tid] - orig;
  curs[tid] = ex;
  const int ebr = e_base(rel);
  const int d = d0 + tid;
  if (d < 30000) offsets[rel * CSTRIDE + d] = (gbeg - ebr) + ex;
  if (bloc == NBR - 1 && tid == 0)
    offsets[rel * CSTRIDE + 30000] = e_base(rel + 1) - ebr;
  __syncthreads();
  for (int i = tid; i < n; i += 256) {
    const unsigned int v = bin[gbeg + i];
    const int pos = atomicAdd(&curs[v >> 16], 1);
    csr[gbeg + pos] = (u16)(v & 0xffffu);
  }
}

// ---------------------------------------------------------------------------
// MFMA transform (R6-proven): [Nx128]@[128x144]; tiles 0..7->z, 8->el/er
// ---------------------------------------------------------------------------
struct XJobs {
  const void* x[8]; const u16* bp[8]; u16* z[8]; float* el[8]; float* er[8];
  int N[8]; int t0[8]; int blk0[9];
};
__device__ void xform_dev(const XJobs& J, int xb, int isbf) {
  __shared__ __align__(16) u16 Bf[18432];
  __shared__ __align__(16) u16 As[64 * 136];
  const int tid = threadIdx.x;
  int job = 0;
  while (xb >= J.blk0[job + 1]) ++job;
  const int row0 = (xb - J.blk0[job]) * 64;
  const int N = J.N[job];
  const int t0 = J.t0[job];
  const u16* bp = J.bp[job];
  const void* x = J.x[job];

  if (t0 == 0) {
    for (int i = tid * 8; i < 18432; i += 2048)
      *(uint4*)&Bf[i] = *(const uint4*)&bp[i];
  } else {
    const int i = tid * 8;
    const int kc = i >> 9;
    const int off = (kc * 144 + 128) * 32 + (i & 511);
    *(uint4*)&Bf[off] = *(const uint4*)&bp[off];
  }

  if (isbf) {
    const uint4* xv = (const uint4*)x;
    for (int i = tid; i < 1024; i += 256) {
      const int r = i >> 4, c8 = i & 15;
      const int row = row0 + r;
      uint4 v = make_uint4(0, 0, 0, 0);
      if (row < N) v = xv[row * 16 + c8];
      *(uint4*)&As[r * 136 + c8 * 8] = v;
    }
  } else {
    const float4* xf = (const float4*)x;
    for (int i = tid; i < 2048; i += 256) {
      const int r = i >> 5, c4 = i & 31;
      const int row = row0 + r;
      unsigned long long pkv = 0ull;
      if (row < N) {
        const float4 v = xf[row * 32 + c4];
        pkv = (unsigned long long)f2bf(v.x) | ((unsigned long long)f2bf(v.y) << 16)
            | ((unsigned long long)f2bf(v.z) << 32) | ((unsigned long long)f2bf(v.w) << 48);
      }
      *(unsigned long long*)&As[r * 136 + c4 * 4] = pkv;
    }
  }
  __syncthreads();

  const int wave = tid >> 6;
  const int lane = tid & 63;
  const int q = lane >> 4;
  const int c = lane & 15;

  f32x4 accT[8];
  f32x4 acc8 = (f32x4){0.f, 0.f, 0.f, 0.f};
  if (t0 == 0) {
    #pragma unroll
    for (int t = 0; t < 8; ++t) accT[t] = (f32x4){0.f, 0.f, 0.f, 0.f};
  }

  #pragma unroll
  for (int kc = 0; kc < 4; ++kc) {
    const short8 a = *(const short8*)&As[(wave * 16 + c) * 136 + kc * 32 + q * 8];
    if (t0 == 0) {
      #pragma unroll
      for (int t = 0; t < 8; ++t) {
        const short8 bb = *(const short8*)&Bf[((kc * 144 + t * 16 + c) * 4 + q) * 8];
        accT[t] = __builtin_amdgcn_mfma_f32_16x16x32_bf16(a, bb, accT[t], 0, 0, 0);
      }
    }
    const short8 b8 = *(const short8*)&Bf[((kc * 144 + 128 + c) * 4 + q) * 8];
    acc8 = __builtin_amdgcn_mfma_f32_16x16x32_bf16(a, b8, acc8, 0, 0, 0);
  }

  const int rbase = row0 + wave * 16 + q * 4;
  if (t0 == 0 && J.z[job]) {
    u16* zo = J.z[job];
    #pragma unroll
    for (int t = 0; t < 8; ++t)
      #pragma unroll
      for (int r = 0; r < 4; ++r) {
        const int row = rbase + r;
        if (row < N) zo[row * 128 + t * 16 + c] = f2bf(accT[t][r]);
      }
  }
  #pragma unroll
  for (int r = 0; r < 4; ++r) {
    const int row = rbase + r;
    if (row < N) {
      const float v = acc8[r];
      if (c < 8) { if (J.el[job]) J.el[job][row * 8 + c] = v; }
      else       { if (J.er[job]) J.er[job][row * 8 + (c - 8)] = v; }
    }
  }
}

// k_l4: blocks 0..589 = fill2, 590.. = xform
__global__ __launch_bounds__(256) void k_l4(XJobs XJ, const void* xdet,
    const unsigned int* __restrict__ bin, const int* __restrict__ totals,
    u16* __restrict__ csr, int* __restrict__ offsets) {
  if (blockIdx.x < NB) {
    fill2_dev(bin, totals, csr, offsets, blockIdx.x);
  } else {
    const int isbf = detect_isbf(xdet);
    xform_dev(XJ, blockIdx.x - NB, isbf);
  }
}

// ---------------------------------------------------------------------------
// Aggregation: one wave per (relation, dst). 8 edges/window; lane (h,i)
// computes ex once; batched phases maximize outstanding loads:
// csr -> 8 readlane -> 8 z loads (back-to-back) -> 8 bpermute -> 16 FMA.
// Tail masked with ex=0 (no divergent tail loop).
// ---------------------------------------------------------------------------
struct AJobs { const u16* csr[5]; const int* off[5]; const float* el[5];
               const float* er[5]; const u16* z[5]; const void* b[5];
               u16* feats[5]; int stride[5]; };
__global__ __launch_bounds__(256) void k_agg_all(AJobs J, const void* xdet) {
  const int isbf = detect_isbf(xdet);
  const int gw = (blockIdx.x * 256 + threadIdx.x) >> 6;
  const int lane = threadIdx.x & 63;
  const int job = gw / 30000;
  const int d = gw - job * 30000;
  const int h = lane >> 3;            // head of this lane's feature pair
  const int i8 = lane & 7;            // which of 8 edges this lane exps
  const float* el = J.el[job];
  const u16* ztl = J.z[job] + lane * 2;   // per-lane z base
  const u16* csr = J.csr[job];
  const float erh = J.er[job][d * 8 + h];
  const int beg = J.off[job][d];
  const int end = J.off[job][d + 1];
  const int gb4 = (lane & 56) << 2;   // bpermute byte base of this h-group

  float a0 = 0.f, a1 = 0.f, denP = 0.f;
  for (int p = beg; p < end; p += 8) {
    const int idx = p + i8;
    const bool valid = (idx < end);
    const int sE = (int)csr[valid ? idx : (end - 1)];
    float eh = el[sE * 8 + h] + erh;
    eh = fminf(fmaxf(eh, 0.2f * eh), 60.f);   // leaky_relu + clamp
    const float exE = valid ? __expf(eh) : 0.f;
    denP += exE;
    int si[8];
    #pragma unroll
    for (int i = 0; i < 8; ++i) si[i] = __builtin_amdgcn_readlane(sE, i);
    unsigned int zp[8];
    #pragma unroll
    for (int i = 0; i < 8; ++i)
      zp[i] = *(const unsigned int*)(ztl + si[i] * 128);
    const int exb = __float_as_int(exE);
    float exi[8];
    #pragma unroll
    for (int i = 0; i < 8; ++i)
      exi[i] = __int_as_float(__builtin_amdgcn_ds_bpermute(gb4 + i * 4, exb));
    #pragma unroll
    for (int i = 0; i < 8; ++i) {
      union { unsigned int u; float f; } lo, hi;
      lo.u = zp[i] << 16; hi.u = zp[i] & 0xffff0000u;
      a0 = fmaf(exi[i], lo.f, a0);
      a1 = fmaf(exi[i], hi.f, a1);
    }
  }
  denP += __shfl_xor(denP, 1);
  denP += __shfl_xor(denP, 2);
  denP += __shfl_xor(denP, 4);        // full den(h) within the 8-lane group
  const float inv = 1.f / fmaxf(denP, 1e-9f);
  const int j0 = lane * 2;
  const float v0 = a0 * inv + ld_in(J.b[job], j0, isbf);
  const float v1 = a1 * inv + ld_in(J.b[job], j0 + 1, isbf);
  const unsigned int packed = (unsigned int)f2bf(v0) | ((unsigned int)f2bf(v1) << 16);
  *(unsigned int*)(J.feats[job] + d * J.stride[job] + j0) = packed;
}

// ---------------------------------------------------------------------------
// MFMA semantic score (R6-proven) + inline detect
// ---------------------------------------------------------------------------
__global__ __launch_bounds__(256) void k_sem_all(
    const u16* __restrict__ f, const u16* __restrict__ w1pack,
    const void* __restrict__ b1, const void* __restrict__ W2,
    const void* __restrict__ b2, float* __restrict__ s_out, int total,
    const void* xdet)
{
  __shared__ __align__(16) u16 Bf[18432];
  __shared__ __align__(16) u16 As[64 * 136];
  __shared__ float b1S[128], W2S[128];
  const int isbf = detect_isbf(xdet);
  const int tid = threadIdx.x;
  const int row0 = blockIdx.x * 64;

  for (int i = tid * 8; i < 18432; i += 2048)
    *(uint4*)&Bf[i] = *(const uint4*)&w1pack[i];
  if (tid < 128) { b1S[tid] = ld_in(b1, tid, isbf); W2S[tid] = ld_in(W2, tid, isbf); }
  {
    const uint4* xv = (const uint4*)f;
    for (int i = tid; i < 1024; i += 256) {
      const int r = i >> 4, c8 = i & 15;
      const int row = row0 + r;
      uint4 v = make_uint4(0, 0, 0, 0);
      if (row < total) v = xv[row * 16 + c8];
      *(uint4*)&As[r * 136 + c8 * 8] = v;
    }
  }
  __syncthreads();

  const int wave = tid >> 6;
  const int lane = tid & 63;
  const int q = lane >> 4;
  const int c = lane & 15;

  f32x4 acc[8];
  #pragma unroll
  for (int t = 0; t < 8; ++t) acc[t] = (f32x4){0.f, 0.f, 0.f, 0.f};

  #pragma unroll
  for (int kc = 0; kc < 4; ++kc) {
    const short8 a = *(const short8*)&As[(wave * 16 + c) * 136 + kc * 32 + q * 8];
    #pragma unroll
    for (int t = 0; t < 8; ++t) {
      const short8 bb = *(const short8*)&Bf[((kc * 144 + t * 16 + c) * 4 + q) * 8];
      acc[t] = __builtin_amdgcn_mfma_f32_16x16x32_bf16(a, bb, acc[t], 0, 0, 0);
    }
  }

  float part[4] = {0.f, 0.f, 0.f, 0.f};
  #pragma unroll
  for (int t = 0; t < 8; ++t) {
    const int n = t * 16 + c;
    const float b1v = b1S[n];
    const float w2v = W2S[n];
    #pragma unroll
    for (int r = 0; r < 4; ++r) {
      const float hv = acc[t][r] + b1v;
      const float e = __expf(2.f * hv);
      const float th = 1.f - 2.f / (e + 1.f);
      part[r] = fmaf(th, w2v, part[r]);
    }
  }
  #pragma unroll
  for (int r = 0; r < 4; ++r) {
    part[r] += __shfl_xor(part[r], 1);
    part[r] += __shfl_xor(part[r], 2);
    part[r] += __shfl_xor(part[r], 4);
    part[r] += __shfl_xor(part[r], 8);
  }
  if (c == 0) {
    const float b2v = ld_in(b2, 0, isbf);
    #pragma unroll
    for (int r = 0; r < 4; ++r) {
      const int row = row0 + wave * 16 + q * 4 + r;
      if (row < total) s_out[row] = part[r] + b2v;
    }
  }
}

// ---------------------------------------------------------------------------
// Combine: 2 dims per thread (u32 feat loads), softmax over R scores.
// ---------------------------------------------------------------------------
__global__ __launch_bounds__(256) void k_combine_all(
    const u16* __restrict__ feats, const float* __restrict__ s,
    void* __restrict__ out, const void* xdet)
{
  const int isbf = detect_isbf(xdet);
  const int i = blockIdx.x * 256 + threadIdx.x;   // u32-pair index
  if (i >= 3840000) return;
  const bool drug = (i < 1920000);
  const int li = drug ? i : i - 1920000;
  const int n = li >> 6;          // 64 u32 per 128-dim row
  const int j2 = li & 63;
  const float* sr = s + (drug ? n * 3 : 90000 + n * 2);
  const u16* fb = feats + (drug ? n * 384 : 11520000 + n * 256) + j2 * 2;
  const float s0v = sr[0];
  const float s1v = sr[1];
  const float s2v = drug ? sr[2] : -3.4e38f;
  const float m = fmaxf(fmaxf(s0v, s1v), s2v);
  const float w0 = __expf(s0v - m);
  const float w1 = __expf(s1v - m);
  const float w2 = drug ? __expf(s2v - m) : 0.f;
  const float inv = 1.f / (w0 + w1 + w2);
  const unsigned int f0 = *(const unsigned int*)(fb);
  const unsigned int f1 = *(const unsigned int*)(fb + 128);
  union { unsigned int u; float f; } t;
  float acc0, acc1;
  t.u = f0 << 16;          acc0 = w0 * t.f;
  t.u = f0 & 0xffff0000u;  acc1 = w0 * t.f;
  t.u = f1 << 16;          acc0 = fmaf(w1, t.f, acc0);
  t.u = f1 & 0xffff0000u;  acc1 = fmaf(w1, t.f, acc1);
  if (drug) {
    const unsigned int f2 = *(const unsigned int*)(fb + 256);
    t.u = f2 << 16;          acc0 = fmaf(w2, t.f, acc0);
    t.u = f2 & 0xffff0000u;  acc1 = fmaf(w2, t.f, acc1);
  }
  acc0 *= inv; acc1 *= inv;
  const int oidx = drug ? i : i;     // flat u32-pair position matches output
  if (isbf) {
    const unsigned int packed = (unsigned int)f2bf(acc0) | ((unsigned int)f2bf(acc1) << 16);
    ((unsigned int*)out)[oidx] = packed;
  } else {
    float2 v; v.x = acc0; v.y = acc1;
    ((float2*)out)[oidx] = v;
  }
}

extern "C" void kernel_launch(void* const* d_in, const int* in_sizes, int n_in,
                              void* d_out, int out_size, void* d_ws, size_t ws_size,
                              hipStream_t stream)
{
  (void)in_sizes; (void)n_in; (void)out_size; (void)ws_size;

  const void* h_drug = d_in[0];
  const void* h_prot = d_in[1];
  const void* h_se   = d_in[2];
  const void* W_dd = d_in[3];  const void* al_dd = d_in[4];
  const void* ar_dd = d_in[5]; const void* b_dd  = d_in[6];
  const void* W_dp = d_in[7];  const void* al_dp = d_in[8];
  const void* ar_dp = d_in[9]; const void* b_dp  = d_in[10];
  const void* W_pd = d_in[11]; const void* al_pd = d_in[12];
  const void* ar_pd = d_in[13];const void* b_pd  = d_in[14];
  const void* W_pp = d_in[15]; const void* al_pp = d_in[16];
  const void* ar_pp = d_in[17];const void* b_pp  = d_in[18];
  const void* W_sd = d_in[19]; const void* al_sd = d_in[20];
  const void* ar_sd = d_in[21];const void* b_sd  = d_in[22];
  const void* W1 = d_in[23];   const void* b1 = d_in[24];
  const void* W2 = d_in[25];   const void* b2 = d_in[26];
  const int* src_dd = (const int*)d_in[27];
  const int* dst_dd = (const int*)d_in[28];
  const int* src_dp = (const int*)d_in[29];
  const int* dst_dp = (const int*)d_in[30];
  const int* src_pd = (const int*)d_in[31];
  const int* dst_pd = (const int*)d_in[32];
  const int* src_pp = (const int*)d_in[33];
  const int* dst_pp = (const int*)d_in[34];
  const int* src_sd = (const int*)d_in[35];
  const int* dst_sd = (const int*)d_in[36];

  // ---- workspace layout (~94.1 MB <= 101.4 MB proven in R6) ----
  char* w = (char*)d_ws;
  float* el5   = (float*)(w);                    // 4,800,000
  float* er5   = (float*)(w + 4800000);          // 4,800,000
  u16* z_dd    = (u16*)(w + 9600000);            // 7,680,000
  u16* z_pd    = (u16*)(w + 17280000);           // 7,680,000
  u16* z_sd    = (u16*)(w + 24960000);           // 2,560,000
  u16* z_dp    = (u16*)(w + 27520000);           // 7,680,000
  u16* z_pp    = (u16*)(w + 35200000);           // 7,680,000
  int* offsets = (int*)(w + 42880000);           // 600,320
  u16* csr     = (u16*)(w + 43480320);           // 9,000,000
  int* ghist   = (int*)(w + 52480320);           // 1,154,040
  int* gcur    = (int*)(w + 53634560);           // 1,154,040
  int* totals  = (int*)(w + 54788608);           // 2,360
  float* s     = (float*)(w + 54791168);         // 600,000
  u16* feats   = (u16*)(w + 55391232);           // 38,400,000 (16B aligned)
  unsigned int* bin = (unsigned int*)(w + 55391232); // aliases feats (dead before agg)
  float* ww    = (float*)(w + 93791232);         // 40,960 (wal/war x5)
  u16* packs   = (u16*)(w + 93832192);           // 221,184 -> end 94,053,376

  float *wal[5], *war[5];
  for (int r = 0; r < 5; ++r) { wal[r] = ww + r * 2048; war[r] = ww + r * 2048 + 1024; }
  u16* pk[6];
  for (int r = 0; r < 6; ++r) pk[r] = packs + r * 18432;
  float* el_r[5]; float* er_r[5];
  for (int r = 0; r < 5; ++r) { el_r[r] = el5 + r * 240000; er_r[r] = er5 + r * 240000; }
  u16* feats_d = feats;               // drug: 30000 x 384
  u16* feats_p = feats + 11520000;    // prot: 30000 x 256

  const dim3 blk(256);

  // rel order: 0=dd 1=pd 2=sd 3=dp 4=pp
  PJobs pj;
  pj.W[0]=W_dd; pj.al[0]=al_dd; pj.ar[0]=ar_dd;
  pj.W[1]=W_pd; pj.al[1]=al_pd; pj.ar[1]=ar_pd;
  pj.W[2]=W_sd; pj.al[2]=al_sd; pj.ar[2]=ar_sd;
  pj.W[3]=W_dp; pj.al[3]=al_dp; pj.ar[3]=ar_dp;
  pj.W[4]=W_pp; pj.al[4]=al_pp; pj.ar[4]=ar_pp;
  for (int r = 0; r < 5; ++r) { pj.wal[r] = wal[r]; pj.war[r] = war[r]; }

  EJobs ej;
  ej.src[0]=src_dd; ej.dst[0]=dst_dd;
  ej.src[1]=src_pd; ej.dst[1]=dst_pd;
  ej.src[2]=src_sd; ej.dst[2]=dst_sd;
  ej.src[3]=src_dp; ej.dst[3]=dst_dp;
  ej.src[4]=src_pp; ej.dst[4]=dst_pp;

  KPack kp;
  kp.W[0]=W_dd; kp.W[1]=W_pd; kp.W[2]=W_sd; kp.W[3]=W_dp; kp.W[4]=W_pp; kp.W[5]=W1;
  for (int r = 0; r < 5; ++r) { kp.wal[r] = wal[r]; kp.war[r] = war[r]; }
  kp.wal[5]=nullptr; kp.war[5]=nullptr;
  for (int r = 0; r < 6; ++r) kp.out[r] = pk[r];

  XJobs xj;
  auto setx = [&](int i, const void* x, const u16* bp, u16* z, float* el,
                  float* er, int N, int t0) {
    xj.x[i]=x; xj.bp[i]=bp; xj.z[i]=z; xj.el[i]=el; xj.er[i]=er; xj.N[i]=N; xj.t0[i]=t0;
  };
  setx(0, h_drug, pk[0], z_dd, el_r[0], er_r[0], ND, 0);   // dd
  setx(1, h_prot, pk[1], z_pd, el_r[1], nullptr, NP, 0);   // pd src
  setx(2, h_drug, pk[1], nullptr, nullptr, er_r[1], ND, 8);// pd dst
  setx(3, h_se,   pk[2], z_sd, el_r[2], nullptr, NS, 0);   // sd src
  setx(4, h_drug, pk[2], nullptr, nullptr, er_r[2], ND, 8);// sd dst
  setx(5, h_drug, pk[3], z_dp, el_r[3], nullptr, ND, 0);   // dp src
  setx(6, h_prot, pk[3], nullptr, nullptr, er_r[3], NP, 8);// dp dst
  setx(7, h_prot, pk[4], z_pp, el_r[4], er_r[4], NP, 0);   // pp
  int xblocks = 0;
  for (int i = 0; i < 8; ++i) { xj.blk0[i] = xblocks; xblocks += (xj.N[i] + 63) / 64; }
  xj.blk0[8] = xblocks;

  AJobs aj;
  const int ebase[5] = {0, 1000000, 2000000, 2500000, 3500000};
  const void* bias[5] = {b_dd, b_pd, b_sd, b_dp, b_pp};
  u16* fb[5] = {feats_d, feats_d + 128, feats_d + 256, feats_p, feats_p + 128};
  const int fstride[5] = {384, 384, 384, 256, 256};
  const u16* zz[5] = {z_dd, z_pd, z_sd, z_dp, z_pp};
  for (int r = 0; r < 5; ++r) {
    aj.csr[r] = csr + ebase[r];
    aj.off[r] = offsets + r * CSTRIDE;
    aj.el[r] = el_r[r];
    aj.er[r] = er_r[r];
    aj.z[r] = zz[r];
    aj.b[r] = bias[r];
    aj.feats[r] = fb[r];
    aj.stride[r] = fstride[r];
  }

  // ---- 7 launches, no memsets ----
  k_front<<<dim3(5 + NC), blk, 0, stream>>>(pj, ej, h_drug, ghist);
  k_mid<<<dim3(54 + NB), blk, 0, stream>>>(kp, h_drug, ghist, gcur, totals);
  k_bin<<<dim3(NC), blk, 0, stream>>>(ej, gcur, totals, bin);
  k_l4<<<dim3(NB + xblocks), blk, 0, stream>>>(xj, h_drug, bin, totals, csr, offsets);
  k_agg_all<<<dim3(37500), blk, 0, stream>>>(aj, h_drug);
  k_sem_all<<<dim3((150000 + 63) / 64), blk, 0, stream>>>(feats, pk[5], b1, W2, b2, s, 150000, h_drug);
  k_combine_all<<<dim3(15000), blk, 0, stream>>>(feats, s, d_out, h_drug);
}